// Round 13
// baseline (933.072 us; speedup 1.0000x reference)
//
#include <hip/hip_runtime.h>
#include <hip/hip_bf16.h>

#define CH    192
#define NB    4
#define NHH   256
#define NWW   256
#define NPOS  (NB*NHH*NWW)   // 262144
#define HEADS 8
#define DH    24
#define WIN   16
#define PS    ((size_t)NPOS*DH)   // head-plane stride (elems)

typedef unsigned short u16;
typedef __bf16 bf16x8 __attribute__((ext_vector_type(8)));
typedef float  f32x4  __attribute__((ext_vector_type(4)));
typedef u16    u16x8  __attribute__((ext_vector_type(8)));
typedef u16    u16x4  __attribute__((ext_vector_type(4)));

__device__ __forceinline__ float b2f(u16 h) {
    union { unsigned int u; float f; } x; x.u = ((unsigned int)h) << 16; return x.f;
}
__device__ __forceinline__ u16 f2b(float f) {   // RNE
    union { float f; unsigned int u; } x; x.f = f;
    return (u16)((x.u + 0x7fffu + ((x.u >> 16) & 1u)) >> 16);
}

// ---------------------------------------------------------------------------
// P0: pack 4 weight matrices (fp32 [o][i]) into MFMA fragment order, bf16.
// ---------------------------------------------------------------------------
__global__ __launch_bounds__(256) void prep_weights(
    const float* __restrict__ w0, const float* __restrict__ w1,
    const float* __restrict__ w2, const float* __restrict__ w3,
    u16* __restrict__ pack)
{
    const int t = blockIdx.x * 256 + threadIdx.x;   // 18432 total
    const int lane = t & 63, g = t >> 6;            // g: 0..287
    const int mat = g / 72;
    const float* w = (mat == 0) ? w0 : (mat == 1) ? w1 : (mat == 2) ? w2 : w3;
    const int nt = (g / 6) % 12, ks = g % 6;
    const float* src = w + (nt*16 + (lane & 15)) * CH + ks*32 + (lane >> 4) * 8;
    const float4 a = *(const float4*)(src);
    const float4 b = *(const float4*)(src + 4);
    u16x8 o;
    o[0]=f2b(a.x); o[1]=f2b(a.y); o[2]=f2b(a.z); o[3]=f2b(a.w);
    o[4]=f2b(b.x); o[5]=f2b(b.y); o[6]=f2b(b.z); o[7]=f2b(b.w);
    *(u16x8*)(pack + (size_t)g*512 + lane*8) = o;
}

// ---------------------------------------------------------------------------
// K1: fused LayerNorm + QKV MFMA GEMM (operand-swapped: D = W * X^T).
// M=32 tile, At swizzled, 25.1 KB LDS, 6 blk/CU. (unchanged)
// ---------------------------------------------------------------------------
__global__ __launch_bounds__(256, 6) void ln_qkv_gemm(
    const float* __restrict__ x, const float* __restrict__ lng, const float* __restrict__ lnb,
    const u16* __restrict__ bpack,
    u16* __restrict__ y0, u16* __restrict__ y1, u16* __restrict__ y2)
{
    __shared__ __align__(16) u16 At[32*192];    // 12,288 B (swizzled)
    __shared__ __align__(16) u16 St32[32*200];  // 12,800 B
    const int t = threadIdx.x, l = t & 63, w = t >> 6;
    const int lr = l & 15, lg = l >> 4;
    const size_t p0 = (size_t)blockIdx.x * 32;

    // ---- LN phase: 8 lanes per row (24 ch each), shfl-reduce, bf16 -> At ----
    {
        const int row = t >> 3, part = t & 7;
        const float* xp = x + (p0 + row) * CH + part * 24;
        float vals[24];
#pragma unroll
        for (int j = 0; j < 6; ++j) {
            float4 v4 = *(const float4*)(xp + j * 4);
            vals[j*4+0]=v4.x; vals[j*4+1]=v4.y; vals[j*4+2]=v4.z; vals[j*4+3]=v4.w;
        }
        float s = 0.f, s2 = 0.f;
#pragma unroll
        for (int j = 0; j < 24; ++j) { s += vals[j]; s2 += vals[j]*vals[j]; }
        s += __shfl_xor(s, 1);  s2 += __shfl_xor(s2, 1);
        s += __shfl_xor(s, 2);  s2 += __shfl_xor(s2, 2);
        s += __shfl_xor(s, 4);  s2 += __shfl_xor(s2, 4);
        const float mu = s * (1.f/192.f);
        const float rs = rsqrtf(s2 * (1.f/192.f) - mu*mu + 1e-5f);
#pragma unroll
        for (int jb = 0; jb < 3; ++jb) {
            u16x8 o;
#pragma unroll
            for (int j = 0; j < 8; ++j) {
                const int c = part*24 + jb*8 + j;
                o[j] = f2b((vals[jb*8+j] - mu) * rs * lng[c] + lnb[c]);
            }
            const int cb = part*3 + jb;               // 0..23
            *(u16x8*)&At[row*192 + (cb ^ (row & 7))*8] = o;
        }
    }
    __syncthreads();

    // ---- GEMM over 3 weight matrices (operand-swapped) ----
    for (int mat = 0; mat < 3; ++mat) {
        u16* yb = (mat == 0) ? y0 : (mat == 1) ? y1 : y2;
        f32x4 acc[2][3];
#pragma unroll
        for (int mt = 0; mt < 2; ++mt)
#pragma unroll
            for (int nt = 0; nt < 3; ++nt) acc[mt][nt] = (f32x4){0.f,0.f,0.f,0.f};
        const u16* bp = bpack + (size_t)mat*36864 + (size_t)w*3*3072 + l*8;
#pragma unroll
        for (int ks = 0; ks < 6; ++ks) {
            bf16x8 wf[3], xf[2];
#pragma unroll
            for (int nt = 0; nt < 3; ++nt)
                wf[nt] = *(const bf16x8*)(bp + (size_t)nt*3072 + ks*512);
#pragma unroll
            for (int mt = 0; mt < 2; ++mt)
                xf[mt] = *(const bf16x8*)&At[(mt*16 + lr)*192 + ((ks*4 + lg) ^ (lr & 7))*8];
#pragma unroll
            for (int mt = 0; mt < 2; ++mt)
#pragma unroll
                for (int nt = 0; nt < 3; ++nt)   // D = W-frag * X-frag
                    acc[mt][nt] = __builtin_amdgcn_mfma_f32_16x16x32_bf16(
                        wf[nt], xf[mt], acc[mt][nt], 0, 0, 0);
        }
        // D layout: position = mt*16 + lr, channel = (w*3+nt)*16 + lg*4 + reg
        __syncthreads();                 // St32 free (prev mat's drain done)
#pragma unroll
        for (int mt = 0; mt < 2; ++mt)
#pragma unroll
            for (int nt = 0; nt < 3; ++nt) {
                u16x4 pk;
                pk[0] = f2b(acc[mt][nt][0]); pk[1] = f2b(acc[mt][nt][1]);
                pk[2] = f2b(acc[mt][nt][2]); pk[3] = f2b(acc[mt][nt][3]);
                *(u16x4*)&St32[(mt*16 + lr)*200 + (w*3 + nt)*16 + lg*4] = pk;
            }
        __syncthreads();
        // drain: 256 threads = 8 heads x 32 rows, 48B contiguous each
        {
            const int hh = t >> 5, r = t & 31;
            u16* dst = yb + (size_t)hh*PS + (p0 + r)*DH;
#pragma unroll
            for (int j8 = 0; j8 < 3; ++j8)
                *(u16x8*)(dst + j8*8) = *(const u16x8*)&St32[r*200 + hh*24 + j8*8];
        }
    }
}

// ---------------------------------------------------------------------------
// K2: 3x3 depthwise conv, bf16, fp32 accum, y-coarsened: each thread
// computes 4 output rows (y0..y0+3) for one (x, c8). Loads 6 rows x 3 cols
// = 18 u16x8 for 4 outputs (4.5/output, was 9); tap-outer loop keeps weight
// LDS reads at 18/thread (was 18/output). VALU/output ~160 (was 220) and
// each thread has 4x independent work between load batches — the ILP the
// compiler refused to create across iterations now exists structurally.
// R10-R12 lesson: VGPR knobs don't change the schedule; work-shape does.
// ---------------------------------------------------------------------------
__global__ __launch_bounds__(256, 4) void dwconv_all(
    const u16* __restrict__ in0, const u16* __restrict__ in1, const u16* __restrict__ in2,
    const float* __restrict__ w0, const float* __restrict__ w1, const float* __restrict__ w2,
    u16* __restrict__ out0, u16* __restrict__ out1, u16* __restrict__ out2,
    const u16* __restrict__ zpage)
{
    __shared__ __align__(16) float wloc[9*DH];   // [tap][c], 864 B
    const int z = blockIdx.z;
    const u16* in  = (z == 0) ? in0  : (z == 1) ? in1  : in2;
    const float* wdw = (z == 0) ? w0 : (z == 1) ? w1 : w2;
    u16* out       = (z == 0) ? out0 : (z == 1) ? out1 : out2;
    const int t = threadIdx.x;
    const int h = blockIdx.y;
    if (t < 216) {                        // wdw layout [c][tap] -> wloc [tap][c]
        const int c = t / 9, tap = t - c*9;
        wloc[tap*DH + c] = wdw[h*216 + t];
    }
    __syncthreads();
    // 768 blocks per (h,z); XCD band swizzle (768 % 8 == 0 -> bijective)
    const int bx = blockIdx.x;
    const int swz = (bx & 7)*96 + (bx >> 3);
    const int g = swz*256 + t;               // 0..196607 = quad*3 + c8
    const int c8 = g % 3;
    const int q = g / 3;                     // 0..65535
    const int x = q & 255;
    const int r = q >> 8;                    // b*64 + yg
    const int yg = r & 63, b = r >> 6;
    const int y0 = yg * 4;
    const size_t plane = (size_t)h * PS;

    // issue all 18 row/col loads (borders -> zero page)
    u16x8 iv[18];
#pragma unroll
    for (int rr = 0; rr < 6; ++rr) {
        const int yy = y0 + rr - 1;
        const bool oky = (yy >= 0) && (yy < NHH);
        const u16* rowp = in + plane + (size_t)((b*NHH + yy)*NWW + x)*DH + c8*8;
#pragma unroll
        for (int kx = 0; kx < 3; ++kx) {
            const int xx = x + kx - 1;
            const bool ok = oky && (xx >= 0) && (xx < NWW);
            const u16* src = ok ? (rowp + (kx - 1)*DH) : zpage;
            iv[rr*3 + kx] = *(const u16x8*)src;
        }
    }
    float acc[4][8];
#pragma unroll
    for (int i = 0; i < 4; ++i)
#pragma unroll
        for (int j = 0; j < 8; ++j) acc[i][j] = 0.f;
#pragma unroll
    for (int ky = 0; ky < 3; ++ky)
#pragma unroll
    for (int kx = 0; kx < 3; ++kx) {
        const int tap = ky*3 + kx;
        float wr[8];
        *(float4*)&wr[0] = *(const float4*)&wloc[tap*DH + c8*8];
        *(float4*)&wr[4] = *(const float4*)&wloc[tap*DH + c8*8 + 4];
#pragma unroll
        for (int i = 0; i < 4; ++i) {
            const u16x8 v = iv[(i + ky)*3 + kx];
#pragma unroll
            for (int j = 0; j < 8; ++j)
                acc[i][j] += b2f(v[j]) * wr[j];
        }
    }
#pragma unroll
    for (int i = 0; i < 4; ++i) {
        u16x8 ov;
#pragma unroll
        for (int j = 0; j < 8; ++j) ov[j] = f2b(acc[i][j]);
        *(u16x8*)(out + plane + (size_t)((b*NHH + y0 + i)*NWW + x)*DH + c8*8) = ov;
    }
}

// ---------------------------------------------------------------------------
// K3: per-(window, head) channel attention; head-separated I/O.
// ---------------------------------------------------------------------------
__global__ __launch_bounds__(256) void attn_kernel(
    const u16* __restrict__ q, const u16* __restrict__ k, const u16* __restrict__ v,
    const float* __restrict__ rescale, u16* __restrict__ out)
{
    __shared__ float qt[DH][260];
    __shared__ float kt[DH][260];
    float* pbuf = &kt[0][0];            // reused: partials[4*576] + sim/attn[576]
    const int t    = threadIdx.x;
    const int widx = blockIdx.x;        // b*256 + wy*16 + wx
    const int h    = blockIdx.y;
    const int b  = widx >> 8;
    const int wy = (widx >> 4) & 15, wx = widx & 15;
    const int n  = t;
    const int gy = wy*WIN + (n >> 4), gx = wx*WIN + (n & 15);
    const size_t pbase = (size_t)h*PS + (size_t)((b*NHH + gy)*NWW + gx) * DH;

    // phase A: q,k transposed into LDS (fp32)
#pragma unroll
    for (int j8 = 0; j8 < 3; ++j8) {
        const u16x8 qv = *(const u16x8*)(q + pbase + j8*8);
        const u16x8 kv = *(const u16x8*)(k + pbase + j8*8);
#pragma unroll
        for (int j = 0; j < 8; ++j) { qt[j8*8+j][n] = b2f(qv[j]); kt[j8*8+j][n] = b2f(kv[j]); }
    }
    __syncthreads();

    // phase B: sim partials; wave covers 64 of n, thread = 3x3 (i,j) block
    const int wvi  = t >> 6;
    const int lane = t & 63;
    const int i0 = (lane >> 3) * 3, j0 = (lane & 7) * 3;
    float s[3][3];
#pragma unroll
    for (int a2 = 0; a2 < 3; ++a2)
#pragma unroll
        for (int c = 0; c < 3; ++c) s[a2][c] = 0.f;
    for (int nn = wvi*64; nn < wvi*64 + 64; nn += 4) {
        float4 qv[3], kv[3];
#pragma unroll
        for (int a2 = 0; a2 < 3; ++a2) {
            qv[a2] = *(const float4*)&qt[i0+a2][nn];
            kv[a2] = *(const float4*)&kt[j0+a2][nn];
        }
#pragma unroll
        for (int a2 = 0; a2 < 3; ++a2)
#pragma unroll
            for (int c = 0; c < 3; ++c)
                s[a2][c] += qv[a2].x*kv[c].x + qv[a2].y*kv[c].y + qv[a2].z*kv[c].z + qv[a2].w*kv[c].w;
    }
    __syncthreads();

    // phase C: partials -> kt-flat; v -> qt
#pragma unroll
    for (int a2 = 0; a2 < 3; ++a2)
#pragma unroll
        for (int c = 0; c < 3; ++c)
            pbuf[wvi*576 + (i0+a2)*24 + (j0+c)] = s[a2][c];
#pragma unroll
    for (int j8 = 0; j8 < 3; ++j8) {
        const u16x8 vv = *(const u16x8*)(v + pbase + j8*8);
#pragma unroll
        for (int j = 0; j < 8; ++j) qt[j8*8+j][n] = b2f(vv[j]);
    }
    __syncthreads();

    // phase D: reduce 4 wave-partials + rescale
    const float rsc = rescale[h];
    for (int e = t; e < 576; e += 256) {
        const float sum = pbuf[e] + pbuf[576+e] + pbuf[1152+e] + pbuf[1728+e];
        pbuf[2304 + e] = sum * rsc;
    }
    __syncthreads();

    // phase E: softmax over j per row i
    if (t < 24) {
        float* srow = pbuf + 2304 + t*24;
        float m = srow[0];
#pragma unroll
        for (int j = 1; j < 24; ++j) m = fmaxf(m, srow[j]);
        float ssum = 0.f;
#pragma unroll
        for (int j = 0; j < 24; ++j) { const float e_ = expf(srow[j] - m); srow[j] = e_; ssum += e_; }
        const float inv = 1.f / ssum;
#pragma unroll
        for (int j = 0; j < 24; ++j) srow[j] *= inv;
    }
    __syncthreads();

    // phase F: PV — thread (iw,nc): 6 i-rows x one 4-wide n-chunk
    const int nc = t & 63;
    const int ib = (t >> 6) * 6;
    float4 acc[6];
#pragma unroll
    for (int ii = 0; ii < 6; ++ii) acc[ii] = make_float4(0.f,0.f,0.f,0.f);
#pragma unroll
    for (int j = 0; j < 24; ++j) {
        const float4 vj = *(const float4*)&qt[j][nc*4];
        const float aw0 = pbuf[2304 + (ib+0)*24 + j];
        const float aw1 = pbuf[2304 + (ib+1)*24 + j];
        const float aw2 = pbuf[2304 + (ib+2)*24 + j];
        const float aw3 = pbuf[2304 + (ib+3)*24 + j];
        const float aw4 = pbuf[2304 + (ib+4)*24 + j];
        const float aw5 = pbuf[2304 + (ib+5)*24 + j];
        acc[0].x += aw0*vj.x; acc[0].y += aw0*vj.y; acc[0].z += aw0*vj.z; acc[0].w += aw0*vj.w;
        acc[1].x += aw1*vj.x; acc[1].y += aw1*vj.y; acc[1].z += aw1*vj.z; acc[1].w += aw1*vj.w;
        acc[2].x += aw2*vj.x; acc[2].y += aw2*vj.y; acc[2].z += aw2*vj.z; acc[2].w += aw2*vj.w;
        acc[3].x += aw3*vj.x; acc[3].y += aw3*vj.y; acc[3].z += aw3*vj.z; acc[3].w += aw3*vj.w;
        acc[4].x += aw4*vj.x; acc[4].y += aw4*vj.y; acc[4].z += aw4*vj.z; acc[4].w += aw4*vj.w;
        acc[5].x += aw5*vj.x; acc[5].y += aw5*vj.y; acc[5].z += aw5*vj.z; acc[5].w += aw5*vj.w;
    }
    __syncthreads();
    // phase G: stage output fp32 into qt
#pragma unroll
    for (int ii = 0; ii < 6; ++ii)
        *(float4*)&qt[ib+ii][nc*4] = acc[ii];
    __syncthreads();
    // phase H: coalesced bf16 store (3KB contiguous per wave)
#pragma unroll
    for (int j8 = 0; j8 < 3; ++j8) {
        u16x8 o;
#pragma unroll
        for (int j = 0; j < 8; ++j) o[j] = f2b(qt[j8*8+j][n]);
        *(u16x8*)(out + pbase + j8*8) = o;
    }
}

// ---------------------------------------------------------------------------
// K4: out-projection MFMA GEMM with LDS-staged A (coalesced) + staged fp32 out.
// ---------------------------------------------------------------------------
__global__ __launch_bounds__(256) void outproj_gemm(
    const u16* __restrict__ a, const u16* __restrict__ bpack, float* __restrict__ yf)
{
    __shared__ __align__(16) u16 At[64*192];    // 24,576 B (swizzled)
    __shared__ __align__(16) float Sf[32*196];  // 25,088 B
    const int t = threadIdx.x, l = t & 63, w = t >> 6;
    const int lr = l & 15, lg = l >> 4;
    const size_t p0 = (size_t)blockIdx.x * 64;

    // stage A-tile: coalesced within head planes (contiguous 4.6KB per plane)
#pragma unroll
    for (int i = 0; i < 6; ++i) {
        const int idx = t + i*256;          // 0..1535 = h*192 + r*3 + c8
        const int h = idx / 192;
        const int rem = idx - h*192;
        const int r = rem / 3, c8 = rem - r*3;
        const u16x8 vv = *(const u16x8*)(a + (size_t)h*PS + (p0 + r)*DH + c8*8);
        *(u16x8*)&At[r*192 + (((h*3 + c8) ^ (r & 7))*8)] = vv;
    }
    __syncthreads();

    f32x4 acc[4][3];
#pragma unroll
    for (int mt = 0; mt < 4; ++mt)
#pragma unroll
        for (int nt = 0; nt < 3; ++nt) acc[mt][nt] = (f32x4){0.f,0.f,0.f,0.f};
    const u16* bp = bpack + (size_t)3*36864 + (size_t)w*3*3072 + l*8;
#pragma unroll
    for (int ks = 0; ks < 6; ++ks) {
        bf16x8 af[4], bfr[3];
#pragma unroll
        for (int nt = 0; nt < 3; ++nt)
            bfr[nt] = *(const bf16x8*)(bp + (size_t)nt*3072 + ks*512);
#pragma unroll
        for (int mt = 0; mt < 4; ++mt)
            af[mt] = *(const bf16x8*)&At[(mt*16 + lr)*192 + ((ks*4 + lg) ^ (lr & 7))*8];
#pragma unroll
        for (int mt = 0; mt < 4; ++mt)
#pragma unroll
            for (int nt = 0; nt < 3; ++nt)
                acc[mt][nt] = __builtin_amdgcn_mfma_f32_16x16x32_bf16(
                    af[mt], bfr[nt], acc[mt][nt], 0, 0, 0);
    }
    // D layout: position = mt*16 + lg*4 + reg, channel = (w*3+nt)*16 + lr
#pragma unroll
    for (int h2 = 0; h2 < 2; ++h2) {
        if (h2) __syncthreads();            // prev drain readers done
#pragma unroll
        for (int mi = 0; mi < 2; ++mi) {
            const int mt = h2*2 + mi;
#pragma unroll
            for (int nt = 0; nt < 3; ++nt)
#pragma unroll
                for (int reg = 0; reg < 4; ++reg)
                    Sf[(mi*16 + lg*4 + reg)*196 + (w*3 + nt)*16 + lr] = acc[mt][nt][reg];
        }
        __syncthreads();
        // drain: 32 rows x 192 ch fp32, fully contiguous 4KB runs
#pragma unroll
        for (int i = 0; i < 6; ++i) {
            const int f = t + i*256;        // 32 rows x 48 float4
            const int row = f / 48, c4 = f - row*48;
            *(float4*)(yf + (p0 + h2*32 + row)*CH + c4*4) = *(const float4*)&Sf[row*196 + c4*4];
        }
    }
}

// ---------------------------------------------------------------------------
extern "C" void kernel_launch(void* const* d_in, const int* in_sizes, int n_in,
                              void* d_out, int out_size, void* d_ws, size_t ws_size,
                              hipStream_t stream)
{
    (void)in_sizes; (void)n_in; (void)out_size; (void)ws_size;
    const float* x     = (const float*)d_in[0];
    const float* ln_g  = (const float*)d_in[1];
    const float* ln_b  = (const float*)d_in[2];
    const float* wq1   = (const float*)d_in[3];
    const float* wq2   = (const float*)d_in[4];
    const float* wk1   = (const float*)d_in[5];
    const float* wk2   = (const float*)d_in[6];
    const float* wv1   = (const float*)d_in[7];
    const float* wv2   = (const float*)d_in[8];
    const float* rsc   = (const float*)d_in[9];
    const float* w_out = (const float*)d_in[10];
    float* out = (float*)d_out;

    const size_t NT = (size_t)NPOS * CH;    // 50,331,648 elems
    u16* u1 = (u16*)d_ws;                   // q,k,v pre-dwconv (head-sep)
    u16* u2 = u1 + NT;
    u16* u3 = u2 + NT;
    u16* u4 = u3 + NT;                      // q,k,v post-dwconv (disjoint)
    u16* u5 = u4 + NT;
    u16* u6 = u5 + NT;
    u16* pack = u6 + NT;                    // 147,456 u16
    u16* zpage = pack + 147456;             // 512 B zero page (16B-aligned)

    hipMemsetAsync(zpage, 0, 512, stream);
    prep_weights<<<72, 256, 0, stream>>>(wq1, wk1, wv1, w_out, pack);
    // fused LN + QKV GEMM -> head-separated q,k,v
    ln_qkv_gemm<<<NPOS/32, 256, 0, stream>>>(x, ln_g, ln_b, pack, u1, u2, u3);
    // depthwise 3x3, y-coarsened 4px/thread: grid (768, heads, tensor)
    dwconv_all<<<dim3(768, HEADS, 3), 256, 0, stream>>>(
        u1, u2, u3, wq2, wk2, wv2, u4, u5, u6, zpage);
    // windowed channel attention: q=u4, k=u5, v=u6 -> u1 (head-sep)
    attn_kernel<<<dim3(NB*256, HEADS), 256, 0, stream>>>(u4, u5, u6, rsc, u1);
    // output projection (A staged in LDS, fp32 NHWC out)
    outproj_gemm<<<NPOS/64, 256, 0, stream>>>(u1, pack, out);
}

// Round 14
// 593.579 us; speedup vs baseline: 1.5719x; 1.5719x over previous
//
#include <hip/hip_runtime.h>
#include <hip/hip_bf16.h>

#define CH    192
#define NB    4
#define NHH   256
#define NWW   256
#define NPOS  (NB*NHH*NWW)   // 262144
#define HEADS 8
#define DH    24
#define WIN   16
#define PS    ((size_t)NPOS*DH)   // head-plane stride (elems)

typedef unsigned short u16;
typedef __bf16 bf16x8 __attribute__((ext_vector_type(8)));
typedef float  f32x4  __attribute__((ext_vector_type(4)));
typedef u16    u16x8  __attribute__((ext_vector_type(8)));
typedef u16    u16x4  __attribute__((ext_vector_type(4)));

__device__ __forceinline__ float b2f(u16 h) {
    union { unsigned int u; float f; } x; x.u = ((unsigned int)h) << 16; return x.f;
}
__device__ __forceinline__ u16 f2b(float f) {   // RNE
    union { float f; unsigned int u; } x; x.f = f;
    return (u16)((x.u + 0x7fffu + ((x.u >> 16) & 1u)) >> 16);
}

// ---------------------------------------------------------------------------
// P0: pack 4 weight matrices (fp32 [o][i]) into MFMA fragment order, bf16.
// ---------------------------------------------------------------------------
__global__ __launch_bounds__(256) void prep_weights(
    const float* __restrict__ w0, const float* __restrict__ w1,
    const float* __restrict__ w2, const float* __restrict__ w3,
    u16* __restrict__ pack)
{
    const int t = blockIdx.x * 256 + threadIdx.x;   // 18432 total
    const int lane = t & 63, g = t >> 6;            // g: 0..287
    const int mat = g / 72;
    const float* w = (mat == 0) ? w0 : (mat == 1) ? w1 : (mat == 2) ? w2 : w3;
    const int nt = (g / 6) % 12, ks = g % 6;
    const float* src = w + (nt*16 + (lane & 15)) * CH + ks*32 + (lane >> 4) * 8;
    const float4 a = *(const float4*)(src);
    const float4 b = *(const float4*)(src + 4);
    u16x8 o;
    o[0]=f2b(a.x); o[1]=f2b(a.y); o[2]=f2b(a.z); o[3]=f2b(a.w);
    o[4]=f2b(b.x); o[5]=f2b(b.y); o[6]=f2b(b.z); o[7]=f2b(b.w);
    *(u16x8*)(pack + (size_t)g*512 + lane*8) = o;
}

// ---------------------------------------------------------------------------
// K1: fused LayerNorm + QKV MFMA GEMM (operand-swapped: D = W * X^T).
// M=32 tile. LDS diet: At 12.3 KB + St16 [16][200] 6.4 KB = 18.7 KB ->
// 8 blocks/CU = 32 waves/CU (HW max) with __launch_bounds__(256,8)
// (acc is only 24 VGPRs, so the 64-VGPR cap at 8 waves/SIMD fits —
// unlike dwconv, whose 72-reg halo spilled in R13). Targets the
// everything-idle latency-bound profile (Occ 21%, all pipes <30%).
// ---------------------------------------------------------------------------
__global__ __launch_bounds__(256, 8) void ln_qkv_gemm(
    const float* __restrict__ x, const float* __restrict__ lng, const float* __restrict__ lnb,
    const u16* __restrict__ bpack,
    u16* __restrict__ y0, u16* __restrict__ y1, u16* __restrict__ y2)
{
    __shared__ __align__(16) u16 At[32*192];    // 12,288 B (swizzled)
    __shared__ __align__(16) u16 St16[16*200];  //  6,400 B
    const int t = threadIdx.x, l = t & 63, w = t >> 6;
    const int lr = l & 15, lg = l >> 4;
    const size_t p0 = (size_t)blockIdx.x * 32;

    // ---- LN phase: 8 lanes per row (24 ch each), shfl-reduce, bf16 -> At ----
    {
        const int row = t >> 3, part = t & 7;
        const float* xp = x + (p0 + row) * CH + part * 24;
        float vals[24];
#pragma unroll
        for (int j = 0; j < 6; ++j) {
            float4 v4 = *(const float4*)(xp + j * 4);
            vals[j*4+0]=v4.x; vals[j*4+1]=v4.y; vals[j*4+2]=v4.z; vals[j*4+3]=v4.w;
        }
        float s = 0.f, s2 = 0.f;
#pragma unroll
        for (int j = 0; j < 24; ++j) { s += vals[j]; s2 += vals[j]*vals[j]; }
        s += __shfl_xor(s, 1);  s2 += __shfl_xor(s2, 1);
        s += __shfl_xor(s, 2);  s2 += __shfl_xor(s2, 2);
        s += __shfl_xor(s, 4);  s2 += __shfl_xor(s2, 4);
        const float mu = s * (1.f/192.f);
        const float rs = rsqrtf(s2 * (1.f/192.f) - mu*mu + 1e-5f);
#pragma unroll
        for (int jb = 0; jb < 3; ++jb) {
            u16x8 o;
#pragma unroll
            for (int j = 0; j < 8; ++j) {
                const int c = part*24 + jb*8 + j;
                o[j] = f2b((vals[jb*8+j] - mu) * rs * lng[c] + lnb[c]);
            }
            const int cb = part*3 + jb;               // 0..23
            *(u16x8*)&At[row*192 + (cb ^ (row & 7))*8] = o;
        }
    }
    __syncthreads();

    // ---- GEMM over 3 weight matrices (operand-swapped) ----
    for (int mat = 0; mat < 3; ++mat) {
        u16* yb = (mat == 0) ? y0 : (mat == 1) ? y1 : y2;
        f32x4 acc[2][3];
#pragma unroll
        for (int mt = 0; mt < 2; ++mt)
#pragma unroll
            for (int nt = 0; nt < 3; ++nt) acc[mt][nt] = (f32x4){0.f,0.f,0.f,0.f};
        const u16* bp = bpack + (size_t)mat*36864 + (size_t)w*3*3072 + l*8;
#pragma unroll
        for (int ks = 0; ks < 6; ++ks) {
            bf16x8 wf[3], xf[2];
#pragma unroll
            for (int nt = 0; nt < 3; ++nt)
                wf[nt] = *(const bf16x8*)(bp + (size_t)nt*3072 + ks*512);
#pragma unroll
            for (int mt = 0; mt < 2; ++mt)
                xf[mt] = *(const bf16x8*)&At[(mt*16 + lr)*192 + ((ks*4 + lg) ^ (lr & 7))*8];
#pragma unroll
            for (int mt = 0; mt < 2; ++mt)
#pragma unroll
                for (int nt = 0; nt < 3; ++nt)   // D = W-frag * X-frag
                    acc[mt][nt] = __builtin_amdgcn_mfma_f32_16x16x32_bf16(
                        wf[nt], xf[mt], acc[mt][nt], 0, 0, 0);
        }
        // D layout: position = mt*16 + lr, channel = (w*3+nt)*16 + lg*4 + reg
#pragma unroll
        for (int h2 = 0; h2 < 2; ++h2) {     // 16-row halves through St16
            __syncthreads();                 // St16 free (prev drain done)
#pragma unroll
            for (int nt = 0; nt < 3; ++nt) {
                u16x4 pk;
                pk[0] = f2b(acc[h2][nt][0]); pk[1] = f2b(acc[h2][nt][1]);
                pk[2] = f2b(acc[h2][nt][2]); pk[3] = f2b(acc[h2][nt][3]);
                *(u16x4*)&St16[lr*200 + (w*3 + nt)*16 + lg*4] = pk;
            }
            __syncthreads();
            // drain: 128 threads = 8 heads x 16 rows, 48B contiguous each
            if (t < 128) {
                const int hh = t >> 4, r = t & 15;
                u16* dst = yb + (size_t)hh*PS + (p0 + h2*16 + r)*DH;
#pragma unroll
                for (int j8 = 0; j8 < 3; ++j8)
                    *(u16x8*)(dst + j8*8) = *(const u16x8*)&St16[r*200 + hh*24 + j8*8];
            }
        }
    }
}

// ---------------------------------------------------------------------------
// K2: 3x3 depthwise conv per head-plane [h][b][y][x][24], bf16, fp32 accum.
// EXACT R12 version (194 us, VGPR 32): LDS weights [tap][c], batched iv[9],
// zpage borders, XCD band swizzle, lb(256,4). R13's y-coarsening (iv[18],
// 72 live regs) spilled to scratch at the 64-VGPR schedule -> 1.4 GB of
// spill traffic. This kernel's plateau is here; do not restructure again.
// ---------------------------------------------------------------------------
__global__ __launch_bounds__(256, 4) void dwconv_all(
    const u16* __restrict__ in0, const u16* __restrict__ in1, const u16* __restrict__ in2,
    const float* __restrict__ w0, const float* __restrict__ w1, const float* __restrict__ w2,
    u16* __restrict__ out0, u16* __restrict__ out1, u16* __restrict__ out2,
    const u16* __restrict__ zpage)
{
    __shared__ __align__(16) float wloc[9*DH];   // [tap][c], 864 B
    const int z = blockIdx.z;
    const u16* in  = (z == 0) ? in0  : (z == 1) ? in1  : in2;
    const float* wdw = (z == 0) ? w0 : (z == 1) ? w1 : w2;
    u16* out       = (z == 0) ? out0 : (z == 1) ? out1 : out2;
    const int t = threadIdx.x;
    const int h = blockIdx.y;
    if (t < 216) {                        // wdw layout [c][tap] -> wloc [tap][c]
        const int c = t / 9, tap = t - c*9;
        wloc[tap*DH + c] = wdw[h*216 + t];
    }
    __syncthreads();
    const int NSLICE = NPOS*3/256;           // 3072 blocks per (h,z) slice
    const int CPX = NSLICE/8;                // 384 contiguous blocks per XCD
    const int bx = blockIdx.x;
    const int swz = (bx & 7)*CPX + (bx >> 3);
    const int gid2 = swz * 256 + t;          // in [0, NPOS*3)
    const int p  = gid2 / 3, c8 = gid2 - p*3;
    const int x = p & 255, y = (p >> 8) & 255, b = p >> 16;
    const size_t plane = (size_t)h * PS;

    // issue all 9 tap loads (borders -> zero page), then one wait
    u16x8 iv[9];
#pragma unroll
    for (int ky = 0; ky < 3; ++ky) {
        const int yy = y + ky - 1;
        const bool oky = (yy >= 0) && (yy < NHH);
        const u16* rowp = in + plane + (size_t)((b*NHH + yy)*NWW + x)*DH + c8*8;
#pragma unroll
        for (int kx = 0; kx < 3; ++kx) {
            const int xx = x + kx - 1;
            const bool ok = oky && (xx >= 0) && (xx < NWW);
            const u16* src = ok ? (rowp + (kx - 1)*DH) : zpage;
            iv[ky*3 + kx] = *(const u16x8*)src;
        }
    }
    float acc[8] = {0,0,0,0,0,0,0,0};
#pragma unroll
    for (int tap = 0; tap < 9; ++tap) {
        float wr[8];
        *(float4*)&wr[0] = *(const float4*)&wloc[tap*DH + c8*8];
        *(float4*)&wr[4] = *(const float4*)&wloc[tap*DH + c8*8 + 4];
#pragma unroll
        for (int j = 0; j < 8; ++j)
            acc[j] += b2f(iv[tap][j]) * wr[j];
    }
    u16x8 ov;
#pragma unroll
    for (int j = 0; j < 8; ++j) ov[j] = f2b(acc[j]);
    *(u16x8*)(out + plane + (size_t)p*DH + c8*8) = ov;
}

// ---------------------------------------------------------------------------
// K3: per-(window, head) channel attention; head-separated I/O.
// ---------------------------------------------------------------------------
__global__ __launch_bounds__(256) void attn_kernel(
    const u16* __restrict__ q, const u16* __restrict__ k, const u16* __restrict__ v,
    const float* __restrict__ rescale, u16* __restrict__ out)
{
    __shared__ float qt[DH][260];
    __shared__ float kt[DH][260];
    float* pbuf = &kt[0][0];            // reused: partials[4*576] + sim/attn[576]
    const int t    = threadIdx.x;
    const int widx = blockIdx.x;        // b*256 + wy*16 + wx
    const int h    = blockIdx.y;
    const int b  = widx >> 8;
    const int wy = (widx >> 4) & 15, wx = widx & 15;
    const int n  = t;
    const int gy = wy*WIN + (n >> 4), gx = wx*WIN + (n & 15);
    const size_t pbase = (size_t)h*PS + (size_t)((b*NHH + gy)*NWW + gx) * DH;

    // phase A: q,k transposed into LDS (fp32)
#pragma unroll
    for (int j8 = 0; j8 < 3; ++j8) {
        const u16x8 qv = *(const u16x8*)(q + pbase + j8*8);
        const u16x8 kv = *(const u16x8*)(k + pbase + j8*8);
#pragma unroll
        for (int j = 0; j < 8; ++j) { qt[j8*8+j][n] = b2f(qv[j]); kt[j8*8+j][n] = b2f(kv[j]); }
    }
    __syncthreads();

    // phase B: sim partials; wave covers 64 of n, thread = 3x3 (i,j) block
    const int wvi  = t >> 6;
    const int lane = t & 63;
    const int i0 = (lane >> 3) * 3, j0 = (lane & 7) * 3;
    float s[3][3];
#pragma unroll
    for (int a2 = 0; a2 < 3; ++a2)
#pragma unroll
        for (int c = 0; c < 3; ++c) s[a2][c] = 0.f;
    for (int nn = wvi*64; nn < wvi*64 + 64; nn += 4) {
        float4 qv[3], kv[3];
#pragma unroll
        for (int a2 = 0; a2 < 3; ++a2) {
            qv[a2] = *(const float4*)&qt[i0+a2][nn];
            kv[a2] = *(const float4*)&kt[j0+a2][nn];
        }
#pragma unroll
        for (int a2 = 0; a2 < 3; ++a2)
#pragma unroll
            for (int c = 0; c < 3; ++c)
                s[a2][c] += qv[a2].x*kv[c].x + qv[a2].y*kv[c].y + qv[a2].z*kv[c].z + qv[a2].w*kv[c].w;
    }
    __syncthreads();

    // phase C: partials -> kt-flat; v -> qt
#pragma unroll
    for (int a2 = 0; a2 < 3; ++a2)
#pragma unroll
        for (int c = 0; c < 3; ++c)
            pbuf[wvi*576 + (i0+a2)*24 + (j0+c)] = s[a2][c];
#pragma unroll
    for (int j8 = 0; j8 < 3; ++j8) {
        const u16x8 vv = *(const u16x8*)(v + pbase + j8*8);
#pragma unroll
        for (int j = 0; j < 8; ++j) qt[j8*8+j][n] = b2f(vv[j]);
    }
    __syncthreads();

    // phase D: reduce 4 wave-partials + rescale
    const float rsc = rescale[h];
    for (int e = t; e < 576; e += 256) {
        const float sum = pbuf[e] + pbuf[576+e] + pbuf[1152+e] + pbuf[1728+e];
        pbuf[2304 + e] = sum * rsc;
    }
    __syncthreads();

    // phase E: softmax over j per row i
    if (t < 24) {
        float* srow = pbuf + 2304 + t*24;
        float m = srow[0];
#pragma unroll
        for (int j = 1; j < 24; ++j) m = fmaxf(m, srow[j]);
        float ssum = 0.f;
#pragma unroll
        for (int j = 0; j < 24; ++j) { const float e_ = expf(srow[j] - m); srow[j] = e_; ssum += e_; }
        const float inv = 1.f / ssum;
#pragma unroll
        for (int j = 0; j < 24; ++j) srow[j] *= inv;
    }
    __syncthreads();

    // phase F: PV — thread (iw,nc): 6 i-rows x one 4-wide n-chunk
    const int nc = t & 63;
    const int ib = (t >> 6) * 6;
    float4 acc[6];
#pragma unroll
    for (int ii = 0; ii < 6; ++ii) acc[ii] = make_float4(0.f,0.f,0.f,0.f);
#pragma unroll
    for (int j = 0; j < 24; ++j) {
        const float4 vj = *(const float4*)&qt[j][nc*4];
        const float aw0 = pbuf[2304 + (ib+0)*24 + j];
        const float aw1 = pbuf[2304 + (ib+1)*24 + j];
        const float aw2 = pbuf[2304 + (ib+2)*24 + j];
        const float aw3 = pbuf[2304 + (ib+3)*24 + j];
        const float aw4 = pbuf[2304 + (ib+4)*24 + j];
        const float aw5 = pbuf[2304 + (ib+5)*24 + j];
        acc[0].x += aw0*vj.x; acc[0].y += aw0*vj.y; acc[0].z += aw0*vj.z; acc[0].w += aw0*vj.w;
        acc[1].x += aw1*vj.x; acc[1].y += aw1*vj.y; acc[1].z += aw1*vj.z; acc[1].w += aw1*vj.w;
        acc[2].x += aw2*vj.x; acc[2].y += aw2*vj.y; acc[2].z += aw2*vj.z; acc[2].w += aw2*vj.w;
        acc[3].x += aw3*vj.x; acc[3].y += aw3*vj.y; acc[3].z += aw3*vj.z; acc[3].w += aw3*vj.w;
        acc[4].x += aw4*vj.x; acc[4].y += aw4*vj.y; acc[4].z += aw4*vj.z; acc[4].w += aw4*vj.w;
        acc[5].x += aw5*vj.x; acc[5].y += aw5*vj.y; acc[5].z += aw5*vj.z; acc[5].w += aw5*vj.w;
    }
    __syncthreads();
    // phase G: stage output fp32 into qt
#pragma unroll
    for (int ii = 0; ii < 6; ++ii)
        *(float4*)&qt[ib+ii][nc*4] = acc[ii];
    __syncthreads();
    // phase H: coalesced bf16 store (3KB contiguous per wave)
#pragma unroll
    for (int j8 = 0; j8 < 3; ++j8) {
        u16x8 o;
#pragma unroll
        for (int j = 0; j < 8; ++j) o[j] = f2b(qt[j8*8+j][n]);
        *(u16x8*)(out + pbase + j8*8) = o;
    }
}

// ---------------------------------------------------------------------------
// K4: out-projection MFMA GEMM with LDS-staged A (coalesced) + staged fp32 out.
// ---------------------------------------------------------------------------
__global__ __launch_bounds__(256) void outproj_gemm(
    const u16* __restrict__ a, const u16* __restrict__ bpack, float* __restrict__ yf)
{
    __shared__ __align__(16) u16 At[64*192];    // 24,576 B (swizzled)
    __shared__ __align__(16) float Sf[32*196];  // 25,088 B
    const int t = threadIdx.x, l = t & 63, w = t >> 6;
    const int lr = l & 15, lg = l >> 4;
    const size_t p0 = (size_t)blockIdx.x * 64;

    // stage A-tile: coalesced within head planes (contiguous 4.6KB per plane)
#pragma unroll
    for (int i = 0; i < 6; ++i) {
        const int idx = t + i*256;          // 0..1535 = h*192 + r*3 + c8
        const int h = idx / 192;
        const int rem = idx - h*192;
        const int r = rem / 3, c8 = rem - r*3;
        const u16x8 vv = *(const u16x8*)(a + (size_t)h*PS + (p0 + r)*DH + c8*8);
        *(u16x8*)&At[r*192 + (((h*3 + c8) ^ (r & 7))*8)] = vv;
    }
    __syncthreads();

    f32x4 acc[4][3];
#pragma unroll
    for (int mt = 0; mt < 4; ++mt)
#pragma unroll
        for (int nt = 0; nt < 3; ++nt) acc[mt][nt] = (f32x4){0.f,0.f,0.f,0.f};
    const u16* bp = bpack + (size_t)3*36864 + (size_t)w*3*3072 + l*8;
#pragma unroll
    for (int ks = 0; ks < 6; ++ks) {
        bf16x8 af[4], bfr[3];
#pragma unroll
        for (int nt = 0; nt < 3; ++nt)
            bfr[nt] = *(const bf16x8*)(bp + (size_t)nt*3072 + ks*512);
#pragma unroll
        for (int mt = 0; mt < 4; ++mt)
            af[mt] = *(const bf16x8*)&At[(mt*16 + lr)*192 + ((ks*4 + lg) ^ (lr & 7))*8];
#pragma unroll
        for (int mt = 0; mt < 4; ++mt)
#pragma unroll
            for (int nt = 0; nt < 3; ++nt)
                acc[mt][nt] = __builtin_amdgcn_mfma_f32_16x16x32_bf16(
                    af[mt], bfr[nt], acc[mt][nt], 0, 0, 0);
    }
    // D layout: position = mt*16 + lg*4 + reg, channel = (w*3+nt)*16 + lr
#pragma unroll
    for (int h2 = 0; h2 < 2; ++h2) {
        if (h2) __syncthreads();            // prev drain readers done
#pragma unroll
        for (int mi = 0; mi < 2; ++mi) {
            const int mt = h2*2 + mi;
#pragma unroll
            for (int nt = 0; nt < 3; ++nt)
#pragma unroll
                for (int reg = 0; reg < 4; ++reg)
                    Sf[(mi*16 + lg*4 + reg)*196 + (w*3 + nt)*16 + lr] = acc[mt][nt][reg];
        }
        __syncthreads();
        // drain: 32 rows x 192 ch fp32, fully contiguous 4KB runs
#pragma unroll
        for (int i = 0; i < 6; ++i) {
            const int f = t + i*256;        // 32 rows x 48 float4
            const int row = f / 48, c4 = f - row*48;
            *(float4*)(yf + (p0 + h2*32 + row)*CH + c4*4) = *(const float4*)&Sf[row*196 + c4*4];
        }
    }
}

// ---------------------------------------------------------------------------
extern "C" void kernel_launch(void* const* d_in, const int* in_sizes, int n_in,
                              void* d_out, int out_size, void* d_ws, size_t ws_size,
                              hipStream_t stream)
{
    (void)in_sizes; (void)n_in; (void)out_size; (void)ws_size;
    const float* x     = (const float*)d_in[0];
    const float* ln_g  = (const float*)d_in[1];
    const float* ln_b  = (const float*)d_in[2];
    const float* wq1   = (const float*)d_in[3];
    const float* wq2   = (const float*)d_in[4];
    const float* wk1   = (const float*)d_in[5];
    const float* wk2   = (const float*)d_in[6];
    const float* wv1   = (const float*)d_in[7];
    const float* wv2   = (const float*)d_in[8];
    const float* rsc   = (const float*)d_in[9];
    const float* w_out = (const float*)d_in[10];
    float* out = (float*)d_out;

    const size_t NT = (size_t)NPOS * CH;    // 50,331,648 elems
    u16* u1 = (u16*)d_ws;                   // q,k,v pre-dwconv (head-sep)
    u16* u2 = u1 + NT;
    u16* u3 = u2 + NT;
    u16* u4 = u3 + NT;                      // q,k,v post-dwconv (disjoint)
    u16* u5 = u4 + NT;
    u16* u6 = u5 + NT;
    u16* pack = u6 + NT;                    // 147,456 u16
    u16* zpage = pack + 147456;             // 512 B zero page (16B-aligned)

    hipMemsetAsync(zpage, 0, 512, stream);
    prep_weights<<<72, 256, 0, stream>>>(wq1, wk1, wv1, w_out, pack);
    // fused LN + QKV GEMM -> head-separated q,k,v
    ln_qkv_gemm<<<NPOS/32, 256, 0, stream>>>(x, ln_g, ln_b, pack, u1, u2, u3);
    // depthwise 3x3, one dispatch (z = tensor): u1->u4, u2->u5, u3->u6
    dwconv_all<<<dim3(NPOS*3/256, HEADS, 3), 256, 0, stream>>>(
        u1, u2, u3, wq2, wk2, wv2, u4, u5, u6, zpage);
    // windowed channel attention: q=u4, k=u5, v=u6 -> u1 (head-sep)
    attn_kernel<<<dim3(NB*256, HEADS), 256, 0, stream>>>(u4, u5, u6, rsc, u1);
    // output projection (A staged in LDS, fp32 NHWC out)
    outproj_gemm<<<NPOS/64, 256, 0, stream>>>(u1, pack, out);
}

// Round 15
// 568.450 us; speedup vs baseline: 1.6414x; 1.0442x over previous
//
#include <hip/hip_runtime.h>
#include <hip/hip_bf16.h>

#define CH    192
#define NB    4
#define NHH   256
#define NWW   256
#define NPOS  (NB*NHH*NWW)   // 262144
#define HEADS 8
#define DH    24
#define WIN   16
#define PS    ((size_t)NPOS*DH)   // head-plane stride (elems)

typedef unsigned short u16;
typedef __bf16 bf16x8 __attribute__((ext_vector_type(8)));
typedef float  f32x4  __attribute__((ext_vector_type(4)));
typedef u16    u16x8  __attribute__((ext_vector_type(8)));
typedef u16    u16x4  __attribute__((ext_vector_type(4)));

__device__ __forceinline__ float b2f(u16 h) {
    union { unsigned int u; float f; } x; x.u = ((unsigned int)h) << 16; return x.f;
}
__device__ __forceinline__ u16 f2b(float f) {   // RNE
    union { float f; unsigned int u; } x; x.f = f;
    return (u16)((x.u + 0x7fffu + ((x.u >> 16) & 1u)) >> 16);
}

// ---------------------------------------------------------------------------
// P0: pack 4 weight matrices (fp32 [o][i]) into MFMA fragment order, bf16.
// ---------------------------------------------------------------------------
__global__ __launch_bounds__(256) void prep_weights(
    const float* __restrict__ w0, const float* __restrict__ w1,
    const float* __restrict__ w2, const float* __restrict__ w3,
    u16* __restrict__ pack)
{
    const int t = blockIdx.x * 256 + threadIdx.x;   // 18432 total
    const int lane = t & 63, g = t >> 6;            // g: 0..287
    const int mat = g / 72;
    const float* w = (mat == 0) ? w0 : (mat == 1) ? w1 : (mat == 2) ? w2 : w3;
    const int nt = (g / 6) % 12, ks = g % 6;
    const float* src = w + (nt*16 + (lane & 15)) * CH + ks*32 + (lane >> 4) * 8;
    const float4 a = *(const float4*)(src);
    const float4 b = *(const float4*)(src + 4);
    u16x8 o;
    o[0]=f2b(a.x); o[1]=f2b(a.y); o[2]=f2b(a.z); o[3]=f2b(a.w);
    o[4]=f2b(b.x); o[5]=f2b(b.y); o[6]=f2b(b.z); o[7]=f2b(b.w);
    *(u16x8*)(pack + (size_t)g*512 + lane*8) = o;
}

// ---------------------------------------------------------------------------
// K1: fused LayerNorm + QKV MFMA GEMM (operand-swapped: D = W * X^T).
// M=32 tile, At swizzled, St32 full drain, 25.1 KB LDS, lb(256,6).
// EXACT R12 version (~195 us). R14's St16+8blk variant was SLOWER (213):
// occupancy 81% didn't help — kernel sits at its pattern's ~2.5 TB/s
// achieved-BW ceiling. Structurally done; do not touch again.
// ---------------------------------------------------------------------------
__global__ __launch_bounds__(256, 6) void ln_qkv_gemm(
    const float* __restrict__ x, const float* __restrict__ lng, const float* __restrict__ lnb,
    const u16* __restrict__ bpack,
    u16* __restrict__ y0, u16* __restrict__ y1, u16* __restrict__ y2)
{
    __shared__ __align__(16) u16 At[32*192];    // 12,288 B (swizzled)
    __shared__ __align__(16) u16 St32[32*200];  // 12,800 B
    const int t = threadIdx.x, l = t & 63, w = t >> 6;
    const int lr = l & 15, lg = l >> 4;
    const size_t p0 = (size_t)blockIdx.x * 32;

    // ---- LN phase: 8 lanes per row (24 ch each), shfl-reduce, bf16 -> At ----
    {
        const int row = t >> 3, part = t & 7;
        const float* xp = x + (p0 + row) * CH + part * 24;
        float vals[24];
#pragma unroll
        for (int j = 0; j < 6; ++j) {
            float4 v4 = *(const float4*)(xp + j * 4);
            vals[j*4+0]=v4.x; vals[j*4+1]=v4.y; vals[j*4+2]=v4.z; vals[j*4+3]=v4.w;
        }
        float s = 0.f, s2 = 0.f;
#pragma unroll
        for (int j = 0; j < 24; ++j) { s += vals[j]; s2 += vals[j]*vals[j]; }
        s += __shfl_xor(s, 1);  s2 += __shfl_xor(s2, 1);
        s += __shfl_xor(s, 2);  s2 += __shfl_xor(s2, 2);
        s += __shfl_xor(s, 4);  s2 += __shfl_xor(s2, 4);
        const float mu = s * (1.f/192.f);
        const float rs = rsqrtf(s2 * (1.f/192.f) - mu*mu + 1e-5f);
#pragma unroll
        for (int jb = 0; jb < 3; ++jb) {
            u16x8 o;
#pragma unroll
            for (int j = 0; j < 8; ++j) {
                const int c = part*24 + jb*8 + j;
                o[j] = f2b((vals[jb*8+j] - mu) * rs * lng[c] + lnb[c]);
            }
            const int cb = part*3 + jb;               // 0..23
            *(u16x8*)&At[row*192 + (cb ^ (row & 7))*8] = o;
        }
    }
    __syncthreads();

    // ---- GEMM over 3 weight matrices (operand-swapped) ----
    for (int mat = 0; mat < 3; ++mat) {
        u16* yb = (mat == 0) ? y0 : (mat == 1) ? y1 : y2;
        f32x4 acc[2][3];
#pragma unroll
        for (int mt = 0; mt < 2; ++mt)
#pragma unroll
            for (int nt = 0; nt < 3; ++nt) acc[mt][nt] = (f32x4){0.f,0.f,0.f,0.f};
        const u16* bp = bpack + (size_t)mat*36864 + (size_t)w*3*3072 + l*8;
#pragma unroll
        for (int ks = 0; ks < 6; ++ks) {
            bf16x8 wf[3], xf[2];
#pragma unroll
            for (int nt = 0; nt < 3; ++nt)
                wf[nt] = *(const bf16x8*)(bp + (size_t)nt*3072 + ks*512);
#pragma unroll
            for (int mt = 0; mt < 2; ++mt)
                xf[mt] = *(const bf16x8*)&At[(mt*16 + lr)*192 + ((ks*4 + lg) ^ (lr & 7))*8];
#pragma unroll
            for (int mt = 0; mt < 2; ++mt)
#pragma unroll
                for (int nt = 0; nt < 3; ++nt)   // D = W-frag * X-frag
                    acc[mt][nt] = __builtin_amdgcn_mfma_f32_16x16x32_bf16(
                        wf[nt], xf[mt], acc[mt][nt], 0, 0, 0);
        }
        // D layout: position = mt*16 + lr, channel = (w*3+nt)*16 + lg*4 + reg
        __syncthreads();                 // St32 free (prev mat's drain done)
#pragma unroll
        for (int mt = 0; mt < 2; ++mt)
#pragma unroll
            for (int nt = 0; nt < 3; ++nt) {
                u16x4 pk;
                pk[0] = f2b(acc[mt][nt][0]); pk[1] = f2b(acc[mt][nt][1]);
                pk[2] = f2b(acc[mt][nt][2]); pk[3] = f2b(acc[mt][nt][3]);
                *(u16x4*)&St32[(mt*16 + lr)*200 + (w*3 + nt)*16 + lg*4] = pk;
            }
        __syncthreads();
        // drain: 256 threads = 8 heads x 32 rows, 48B contiguous each
        {
            const int hh = t >> 5, r = t & 31;
            u16* dst = yb + (size_t)hh*PS + (p0 + r)*DH;
#pragma unroll
            for (int j8 = 0; j8 < 3; ++j8)
                *(u16x8*)(dst + j8*8) = *(const u16x8*)&St32[r*200 + hh*24 + j8*8];
        }
    }
}

// ---------------------------------------------------------------------------
// K2+K3 fused v2: depthwise 3x3 + windowed channel attention per
// (window, head). R5's failure (188 VGPR, all 3 tensors' halo+acc live)
// fixed: halo staged ONE tensor at a time in LDS H [c8][18][18][8]
// (15.5 KB), dwconv accumulates 8 ch at a time (acc[8] regs) into the
// f32 qt/kt LDS buffers. halo(v) issues before sim (H is free; loads
// hide under sim VALU). Attention phases are byte-identical to the
// proven attn_kernel. LDS 68.1 KB -> 2 blk/CU. Saves the ~600 MB dwconv
// HBM round-trip.
// ---------------------------------------------------------------------------
__global__ __launch_bounds__(256, 2) void dwattn_kernel(
    const u16* __restrict__ q, const u16* __restrict__ k, const u16* __restrict__ v,
    const float* __restrict__ wq2, const float* __restrict__ wk2, const float* __restrict__ wv2,
    const float* __restrict__ rescale, u16* __restrict__ out,
    const u16* __restrict__ zpage)
{
    __shared__ __align__(16) u16 H[7776];        // [c8][18][18][8], 15,552 B
    __shared__ __align__(16) float qt[24*260];   // 24,960 B
    __shared__ __align__(16) float kt[24*260];   // 24,960 B
    __shared__ __align__(16) float wloc[3*216];  // [tensor][tap][c], 2,592 B
    float* pbuf = kt;                            // partials[4*576]+attn[576]

    const int t = threadIdx.x;
    const int bx = blockIdx.x;                   // 1024 windows
    const int widx = (bx & 7)*128 + (bx >> 3);   // XCD band swizzle (1024%8==0)
    const int h = blockIdx.y;
    const int b = widx >> 8;
    const int wy = (widx >> 4) & 15, wx = widx & 15;
    const size_t plane = (size_t)h * PS;

    // dw weights: src [c][tap] -> wloc [tensor][tap][c] (vectorizable reads)
    for (int i = t; i < 648; i += 256) {
        const int tsr = i / 216, r = i - tsr*216;
        const int c = r / 9, tap = r - c*9;
        const float* ws = (tsr == 0) ? wq2 : (tsr == 1) ? wk2 : wv2;
        wloc[tsr*216 + tap*24 + c] = ws[h*216 + c*9 + tap];
    }

    // ---- halo loader: 972 u16x8 chunks (18 rows x 18 px x 3 c8) ----
    auto halo = [&](const u16* __restrict__ src) {
#pragma unroll
        for (int it = 0; it < 4; ++it) {
            const int i = t + it*256;
            if (i < 972) {
                const int hrow = i / 54, chunk = i - hrow*54;
                const int px = chunk / 3, c8 = chunk - px*3;
                const int gy = wy*WIN + hrow - 1, gx = wx*WIN + px - 1;
                const bool ok = (gy >= 0) && (gy < NHH) && (gx >= 0) && (gx < NWW);
                const u16* sp = ok ? (src + plane + (size_t)((b*NHH + gy)*NWW + gx)*DH + c8*8)
                                   : zpage;
                *(u16x8*)&H[c8*2592 + hrow*144 + px*8] = *(const u16x8*)sp;
            }
        }
    };
    // ---- dwconv from H into dst (f32, channel-major [24][260]) ----
    auto dwc = [&](int tsr, float* __restrict__ dst) {
        const int py = t >> 4, pxx = t & 15;
#pragma unroll
        for (int c8 = 0; c8 < 3; ++c8) {
            float acc[8] = {0,0,0,0,0,0,0,0};
#pragma unroll
            for (int ky = 0; ky < 3; ++ky)
#pragma unroll
            for (int kx = 0; kx < 3; ++kx) {
                const u16x8 hv = *(const u16x8*)&H[c8*2592 + (py+ky)*144 + (pxx+kx)*8];
                const float* wr = &wloc[tsr*216 + (ky*3 + kx)*24 + c8*8];
                float w8[8];
                *(float4*)&w8[0] = *(const float4*)wr;
                *(float4*)&w8[4] = *(const float4*)(wr + 4);
#pragma unroll
                for (int j = 0; j < 8; ++j) acc[j] += b2f(hv[j]) * w8[j];
            }
#pragma unroll
            for (int j = 0; j < 8; ++j) dst[(c8*8 + j)*260 + t] = acc[j];
        }
    };

    halo(q);
    __syncthreads();          // halo q + wloc ready
    dwc(0, qt);
    __syncthreads();          // H free
    halo(k);
    __syncthreads();
    dwc(1, kt);
    __syncthreads();          // H free again

    // halo v issues now; its loads hide under the sim VALU below
    halo(v);

    // ---- sim partials (identical to attn phase B) ----
    const int wvi  = t >> 6;
    const int lane = t & 63;
    const int i0 = (lane >> 3) * 3, j0 = (lane & 7) * 3;
    float s[3][3];
#pragma unroll
    for (int a2 = 0; a2 < 3; ++a2)
#pragma unroll
        for (int c = 0; c < 3; ++c) s[a2][c] = 0.f;
    for (int nn = wvi*64; nn < wvi*64 + 64; nn += 4) {
        float4 qv[3], kv[3];
#pragma unroll
        for (int a2 = 0; a2 < 3; ++a2) {
            qv[a2] = *(const float4*)&qt[(i0+a2)*260 + nn];
            kv[a2] = *(const float4*)&kt[(j0+a2)*260 + nn];
        }
#pragma unroll
        for (int a2 = 0; a2 < 3; ++a2)
#pragma unroll
            for (int c = 0; c < 3; ++c)
                s[a2][c] += qv[a2].x*kv[c].x + qv[a2].y*kv[c].y + qv[a2].z*kv[c].z + qv[a2].w*kv[c].w;
    }
    __syncthreads();          // sim done (qt/kt readers), halo v landed

    // partials -> pbuf (kt area); v dwconv -> qt (overwrites q)
#pragma unroll
    for (int a2 = 0; a2 < 3; ++a2)
#pragma unroll
        for (int c = 0; c < 3; ++c)
            pbuf[wvi*576 + (i0+a2)*24 + (j0+c)] = s[a2][c];
    dwc(2, qt);
    __syncthreads();

    // reduce 4 wave-partials + rescale
    const float rsc = rescale[h];
    for (int e = t; e < 576; e += 256) {
        const float sum = pbuf[e] + pbuf[576+e] + pbuf[1152+e] + pbuf[1728+e];
        pbuf[2304 + e] = sum * rsc;
    }
    __syncthreads();

    // softmax over j per row i
    if (t < 24) {
        float* srow = pbuf + 2304 + t*24;
        float m = srow[0];
#pragma unroll
        for (int j = 1; j < 24; ++j) m = fmaxf(m, srow[j]);
        float ssum = 0.f;
#pragma unroll
        for (int j = 0; j < 24; ++j) { const float e_ = expf(srow[j] - m); srow[j] = e_; ssum += e_; }
        const float inv = 1.f / ssum;
#pragma unroll
        for (int j = 0; j < 24; ++j) srow[j] *= inv;
    }
    __syncthreads();

    // PV: thread (iw,nc): 6 i-rows x one 4-wide n-chunk (v in qt)
    const int nc = t & 63;
    const int ib = (t >> 6) * 6;
    float4 acc[6];
#pragma unroll
    for (int ii = 0; ii < 6; ++ii) acc[ii] = make_float4(0.f,0.f,0.f,0.f);
#pragma unroll
    for (int j = 0; j < 24; ++j) {
        const float4 vj = *(const float4*)&qt[j*260 + nc*4];
        const float aw0 = pbuf[2304 + (ib+0)*24 + j];
        const float aw1 = pbuf[2304 + (ib+1)*24 + j];
        const float aw2 = pbuf[2304 + (ib+2)*24 + j];
        const float aw3 = pbuf[2304 + (ib+3)*24 + j];
        const float aw4 = pbuf[2304 + (ib+4)*24 + j];
        const float aw5 = pbuf[2304 + (ib+5)*24 + j];
        acc[0].x += aw0*vj.x; acc[0].y += aw0*vj.y; acc[0].z += aw0*vj.z; acc[0].w += aw0*vj.w;
        acc[1].x += aw1*vj.x; acc[1].y += aw1*vj.y; acc[1].z += aw1*vj.z; acc[1].w += aw1*vj.w;
        acc[2].x += aw2*vj.x; acc[2].y += aw2*vj.y; acc[2].z += aw2*vj.z; acc[2].w += aw2*vj.w;
        acc[3].x += aw3*vj.x; acc[3].y += aw3*vj.y; acc[3].z += aw3*vj.z; acc[3].w += aw3*vj.w;
        acc[4].x += aw4*vj.x; acc[4].y += aw4*vj.y; acc[4].z += aw4*vj.z; acc[4].w += aw4*vj.w;
        acc[5].x += aw5*vj.x; acc[5].y += aw5*vj.y; acc[5].z += aw5*vj.z; acc[5].w += aw5*vj.w;
    }
    __syncthreads();
    // stage output fp32 into qt
#pragma unroll
    for (int ii = 0; ii < 6; ++ii)
        *(float4*)&qt[(ib+ii)*260 + nc*4] = acc[ii];
    __syncthreads();
    // coalesced bf16 store (3KB contiguous per wave)
    const int n = t;
    const int gy2 = wy*WIN + (n >> 4), gx2 = wx*WIN + (n & 15);
    const size_t pbase = plane + (size_t)((b*NHH + gy2)*NWW + gx2) * DH;
#pragma unroll
    for (int j8 = 0; j8 < 3; ++j8) {
        u16x8 o;
#pragma unroll
        for (int j = 0; j < 8; ++j) o[j] = f2b(qt[(j8*8+j)*260 + n]);
        *(u16x8*)(out + pbase + j8*8) = o;
    }
}

// ---------------------------------------------------------------------------
// K4: out-projection MFMA GEMM with LDS-staged A (coalesced) + staged fp32 out.
// ---------------------------------------------------------------------------
__global__ __launch_bounds__(256) void outproj_gemm(
    const u16* __restrict__ a, const u16* __restrict__ bpack, float* __restrict__ yf)
{
    __shared__ __align__(16) u16 At[64*192];    // 24,576 B (swizzled)
    __shared__ __align__(16) float Sf[32*196];  // 25,088 B
    const int t = threadIdx.x, l = t & 63, w = t >> 6;
    const int lr = l & 15, lg = l >> 4;
    const size_t p0 = (size_t)blockIdx.x * 64;

    // stage A-tile: coalesced within head planes (contiguous 4.6KB per plane)
#pragma unroll
    for (int i = 0; i < 6; ++i) {
        const int idx = t + i*256;          // 0..1535 = h*192 + r*3 + c8
        const int h = idx / 192;
        const int rem = idx - h*192;
        const int r = rem / 3, c8 = rem - r*3;
        const u16x8 vv = *(const u16x8*)(a + (size_t)h*PS + (p0 + r)*DH + c8*8);
        *(u16x8*)&At[r*192 + (((h*3 + c8) ^ (r & 7))*8)] = vv;
    }
    __syncthreads();

    f32x4 acc[4][3];
#pragma unroll
    for (int mt = 0; mt < 4; ++mt)
#pragma unroll
        for (int nt = 0; nt < 3; ++nt) acc[mt][nt] = (f32x4){0.f,0.f,0.f,0.f};
    const u16* bp = bpack + (size_t)3*36864 + (size_t)w*3*3072 + l*8;
#pragma unroll
    for (int ks = 0; ks < 6; ++ks) {
        bf16x8 af[4], bfr[3];
#pragma unroll
        for (int nt = 0; nt < 3; ++nt)
            bfr[nt] = *(const bf16x8*)(bp + (size_t)nt*3072 + ks*512);
#pragma unroll
        for (int mt = 0; mt < 4; ++mt)
            af[mt] = *(const bf16x8*)&At[(mt*16 + lr)*192 + ((ks*4 + lg) ^ (lr & 7))*8];
#pragma unroll
        for (int mt = 0; mt < 4; ++mt)
#pragma unroll
            for (int nt = 0; nt < 3; ++nt)
                acc[mt][nt] = __builtin_amdgcn_mfma_f32_16x16x32_bf16(
                    af[mt], bfr[nt], acc[mt][nt], 0, 0, 0);
    }
    // D layout: position = mt*16 + lg*4 + reg, channel = (w*3+nt)*16 + lr
#pragma unroll
    for (int h2 = 0; h2 < 2; ++h2) {
        if (h2) __syncthreads();            // prev drain readers done
#pragma unroll
        for (int mi = 0; mi < 2; ++mi) {
            const int mt = h2*2 + mi;
#pragma unroll
            for (int nt = 0; nt < 3; ++nt)
#pragma unroll
                for (int reg = 0; reg < 4; ++reg)
                    Sf[(mi*16 + lg*4 + reg)*196 + (w*3 + nt)*16 + lr] = acc[mt][nt][reg];
        }
        __syncthreads();
        // drain: 32 rows x 192 ch fp32, fully contiguous 4KB runs
#pragma unroll
        for (int i = 0; i < 6; ++i) {
            const int f = t + i*256;        // 32 rows x 48 float4
            const int row = f / 48, c4 = f - row*48;
            *(float4*)(yf + (p0 + h2*32 + row)*CH + c4*4) = *(const float4*)&Sf[row*196 + c4*4];
        }
    }
}

// ---------------------------------------------------------------------------
extern "C" void kernel_launch(void* const* d_in, const int* in_sizes, int n_in,
                              void* d_out, int out_size, void* d_ws, size_t ws_size,
                              hipStream_t stream)
{
    (void)in_sizes; (void)n_in; (void)out_size; (void)ws_size;
    const float* x     = (const float*)d_in[0];
    const float* ln_g  = (const float*)d_in[1];
    const float* ln_b  = (const float*)d_in[2];
    const float* wq1   = (const float*)d_in[3];
    const float* wq2   = (const float*)d_in[4];
    const float* wk1   = (const float*)d_in[5];
    const float* wk2   = (const float*)d_in[6];
    const float* wv1   = (const float*)d_in[7];
    const float* wv2   = (const float*)d_in[8];
    const float* rsc   = (const float*)d_in[9];
    const float* w_out = (const float*)d_in[10];
    float* out = (float*)d_out;

    const size_t NT = (size_t)NPOS * CH;    // 50,331,648 elems
    u16* u1 = (u16*)d_ws;                   // q,k,v pre-dwconv (head-sep)
    u16* u2 = u1 + NT;
    u16* u3 = u2 + NT;
    u16* u4 = u3 + NT;                      // attn output (head-sep)
    u16* pack = u4 + NT;                    // 147,456 u16
    u16* zpage = pack + 147456;             // 512 B zero page (16B-aligned)

    hipMemsetAsync(zpage, 0, 512, stream);
    prep_weights<<<72, 256, 0, stream>>>(wq1, wk1, wv1, w_out, pack);
    // fused LN + QKV GEMM -> head-separated q,k,v (pre-dwconv)
    ln_qkv_gemm<<<NPOS/32, 256, 0, stream>>>(x, ln_g, ln_b, pack, u1, u2, u3);
    // fused depthwise 3x3 + windowed channel attention -> u4
    dwattn_kernel<<<dim3(1024, HEADS), 256, 0, stream>>>(
        u1, u2, u3, wq2, wk2, wv2, rsc, u4, zpage);
    // output projection (A staged in LDS, fp32 NHWC out)
    outproj_gemm<<<NPOS/64, 256, 0, stream>>>(u4, pack, out);
}

// Round 16
// 564.676 us; speedup vs baseline: 1.6524x; 1.0067x over previous
//
#include <hip/hip_runtime.h>
#include <hip/hip_bf16.h>

#define CH    192
#define NB    4
#define NHH   256
#define NWW   256
#define NPOS  (NB*NHH*NWW)   // 262144
#define HEADS 8
#define DH    24
#define WIN   16
#define PS    ((size_t)NPOS*DH)   // head-plane stride (elems)

typedef unsigned short u16;
typedef __bf16 bf16x8 __attribute__((ext_vector_type(8)));
typedef float  f32x4  __attribute__((ext_vector_type(4)));
typedef u16    u16x8  __attribute__((ext_vector_type(8)));
typedef u16    u16x4  __attribute__((ext_vector_type(4)));

__device__ __forceinline__ float b2f(u16 h) {
    union { unsigned int u; float f; } x; x.u = ((unsigned int)h) << 16; return x.f;
}
__device__ __forceinline__ u16 f2b(float f) {   // RNE
    union { float f; unsigned int u; } x; x.f = f;
    return (u16)((x.u + 0x7fffu + ((x.u >> 16) & 1u)) >> 16);
}

// ---------------------------------------------------------------------------
// P0: pack 4 weight matrices (fp32 [o][i]) into MFMA fragment order, bf16.
// ---------------------------------------------------------------------------
__global__ __launch_bounds__(256) void prep_weights(
    const float* __restrict__ w0, const float* __restrict__ w1,
    const float* __restrict__ w2, const float* __restrict__ w3,
    u16* __restrict__ pack)
{
    const int t = blockIdx.x * 256 + threadIdx.x;   // 18432 total
    const int lane = t & 63, g = t >> 6;            // g: 0..287
    const int mat = g / 72;
    const float* w = (mat == 0) ? w0 : (mat == 1) ? w1 : (mat == 2) ? w2 : w3;
    const int nt = (g / 6) % 12, ks = g % 6;
    const float* src = w + (nt*16 + (lane & 15)) * CH + ks*32 + (lane >> 4) * 8;
    const float4 a = *(const float4*)(src);
    const float4 b = *(const float4*)(src + 4);
    u16x8 o;
    o[0]=f2b(a.x); o[1]=f2b(a.y); o[2]=f2b(a.z); o[3]=f2b(a.w);
    o[4]=f2b(b.x); o[5]=f2b(b.y); o[6]=f2b(b.z); o[7]=f2b(b.w);
    *(u16x8*)(pack + (size_t)g*512 + lane*8) = o;
}

// ---------------------------------------------------------------------------
// K1: fused LayerNorm + QKV MFMA GEMM (operand-swapped: D = W * X^T).
// M=32 tile, At swizzled, St32 full drain, 25.1 KB LDS, lb(256,6).
// Measured ~195 us. Ledger: conflicts-fix null (R6), occupancy-8blk SLOWER
// (R14, 81% occ at 213 us) — sits at its pattern's ~2.5 TB/s achieved-BW
// ceiling. Structurally done.
// ---------------------------------------------------------------------------
__global__ __launch_bounds__(256, 6) void ln_qkv_gemm(
    const float* __restrict__ x, const float* __restrict__ lng, const float* __restrict__ lnb,
    const u16* __restrict__ bpack,
    u16* __restrict__ y0, u16* __restrict__ y1, u16* __restrict__ y2)
{
    __shared__ __align__(16) u16 At[32*192];    // 12,288 B (swizzled)
    __shared__ __align__(16) u16 St32[32*200];  // 12,800 B
    const int t = threadIdx.x, l = t & 63, w = t >> 6;
    const int lr = l & 15, lg = l >> 4;
    const size_t p0 = (size_t)blockIdx.x * 32;

    // ---- LN phase: 8 lanes per row (24 ch each), shfl-reduce, bf16 -> At ----
    {
        const int row = t >> 3, part = t & 7;
        const float* xp = x + (p0 + row) * CH + part * 24;
        float vals[24];
#pragma unroll
        for (int j = 0; j < 6; ++j) {
            float4 v4 = *(const float4*)(xp + j * 4);
            vals[j*4+0]=v4.x; vals[j*4+1]=v4.y; vals[j*4+2]=v4.z; vals[j*4+3]=v4.w;
        }
        float s = 0.f, s2 = 0.f;
#pragma unroll
        for (int j = 0; j < 24; ++j) { s += vals[j]; s2 += vals[j]*vals[j]; }
        s += __shfl_xor(s, 1);  s2 += __shfl_xor(s2, 1);
        s += __shfl_xor(s, 2);  s2 += __shfl_xor(s2, 2);
        s += __shfl_xor(s, 4);  s2 += __shfl_xor(s2, 4);
        const float mu = s * (1.f/192.f);
        const float rs = rsqrtf(s2 * (1.f/192.f) - mu*mu + 1e-5f);
#pragma unroll
        for (int jb = 0; jb < 3; ++jb) {
            u16x8 o;
#pragma unroll
            for (int j = 0; j < 8; ++j) {
                const int c = part*24 + jb*8 + j;
                o[j] = f2b((vals[jb*8+j] - mu) * rs * lng[c] + lnb[c]);
            }
            const int cb = part*3 + jb;               // 0..23
            *(u16x8*)&At[row*192 + (cb ^ (row & 7))*8] = o;
        }
    }
    __syncthreads();

    // ---- GEMM over 3 weight matrices (operand-swapped) ----
    for (int mat = 0; mat < 3; ++mat) {
        u16* yb = (mat == 0) ? y0 : (mat == 1) ? y1 : y2;
        f32x4 acc[2][3];
#pragma unroll
        for (int mt = 0; mt < 2; ++mt)
#pragma unroll
            for (int nt = 0; nt < 3; ++nt) acc[mt][nt] = (f32x4){0.f,0.f,0.f,0.f};
        const u16* bp = bpack + (size_t)mat*36864 + (size_t)w*3*3072 + l*8;
#pragma unroll
        for (int ks = 0; ks < 6; ++ks) {
            bf16x8 wf[3], xf[2];
#pragma unroll
            for (int nt = 0; nt < 3; ++nt)
                wf[nt] = *(const bf16x8*)(bp + (size_t)nt*3072 + ks*512);
#pragma unroll
            for (int mt = 0; mt < 2; ++mt)
                xf[mt] = *(const bf16x8*)&At[(mt*16 + lr)*192 + ((ks*4 + lg) ^ (lr & 7))*8];
#pragma unroll
            for (int mt = 0; mt < 2; ++mt)
#pragma unroll
                for (int nt = 0; nt < 3; ++nt)   // D = W-frag * X-frag
                    acc[mt][nt] = __builtin_amdgcn_mfma_f32_16x16x32_bf16(
                        wf[nt], xf[mt], acc[mt][nt], 0, 0, 0);
        }
        // D layout: position = mt*16 + lr, channel = (w*3+nt)*16 + lg*4 + reg
        __syncthreads();                 // St32 free (prev mat's drain done)
#pragma unroll
        for (int mt = 0; mt < 2; ++mt)
#pragma unroll
            for (int nt = 0; nt < 3; ++nt) {
                u16x4 pk;
                pk[0] = f2b(acc[mt][nt][0]); pk[1] = f2b(acc[mt][nt][1]);
                pk[2] = f2b(acc[mt][nt][2]); pk[3] = f2b(acc[mt][nt][3]);
                *(u16x4*)&St32[(mt*16 + lr)*200 + (w*3 + nt)*16 + lg*4] = pk;
            }
        __syncthreads();
        // drain: 256 threads = 8 heads x 32 rows, 48B contiguous each
        {
            const int hh = t >> 5, r = t & 31;
            u16* dst = yb + (size_t)hh*PS + (p0 + r)*DH;
#pragma unroll
            for (int j8 = 0; j8 < 3; ++j8)
                *(u16x8*)(dst + j8*8) = *(const u16x8*)&St32[r*200 + hh*24 + j8*8];
        }
    }
}

// ---------------------------------------------------------------------------
// K2: 3x3 depthwise conv per head-plane [h][b][y][x][24], bf16, fp32 accum.
// R12 exact (194 us, VGPR 32): LDS weights [tap][c], batched iv[9] + zpage
// borders (R10's win), XCD band swizzle, lb(256,4). Ledger: weight-transpose
// null (R9), SGPR-uniform regression (R11), y-coarsening spilled (R13).
// Plateau — do not restructure.
// ---------------------------------------------------------------------------
__global__ __launch_bounds__(256, 4) void dwconv_all(
    const u16* __restrict__ in0, const u16* __restrict__ in1, const u16* __restrict__ in2,
    const float* __restrict__ w0, const float* __restrict__ w1, const float* __restrict__ w2,
    u16* __restrict__ out0, u16* __restrict__ out1, u16* __restrict__ out2,
    const u16* __restrict__ zpage)
{
    __shared__ __align__(16) float wloc[9*DH];   // [tap][c], 864 B
    const int z = blockIdx.z;
    const u16* in  = (z == 0) ? in0  : (z == 1) ? in1  : in2;
    const float* wdw = (z == 0) ? w0 : (z == 1) ? w1 : w2;
    u16* out       = (z == 0) ? out0 : (z == 1) ? out1 : out2;
    const int t = threadIdx.x;
    const int h = blockIdx.y;
    if (t < 216) {                        // wdw layout [c][tap] -> wloc [tap][c]
        const int c = t / 9, tap = t - c*9;
        wloc[tap*DH + c] = wdw[h*216 + t];
    }
    __syncthreads();
    const int NSLICE = NPOS*3/256;           // 3072 blocks per (h,z) slice
    const int CPX = NSLICE/8;                // 384 contiguous blocks per XCD
    const int bx = blockIdx.x;
    const int swz = (bx & 7)*CPX + (bx >> 3);
    const int gid2 = swz * 256 + t;          // in [0, NPOS*3)
    const int p  = gid2 / 3, c8 = gid2 - p*3;
    const int x = p & 255, y = (p >> 8) & 255, b = p >> 16;
    const size_t plane = (size_t)h * PS;

    // issue all 9 tap loads (borders -> zero page), then one wait
    u16x8 iv[9];
#pragma unroll
    for (int ky = 0; ky < 3; ++ky) {
        const int yy = y + ky - 1;
        const bool oky = (yy >= 0) && (yy < NHH);
        const u16* rowp = in + plane + (size_t)((b*NHH + yy)*NWW + x)*DH + c8*8;
#pragma unroll
        for (int kx = 0; kx < 3; ++kx) {
            const int xx = x + kx - 1;
            const bool ok = oky && (xx >= 0) && (xx < NWW);
            const u16* src = ok ? (rowp + (kx - 1)*DH) : zpage;
            iv[ky*3 + kx] = *(const u16x8*)src;
        }
    }
    float acc[8] = {0,0,0,0,0,0,0,0};
#pragma unroll
    for (int tap = 0; tap < 9; ++tap) {
        float wr[8];
        *(float4*)&wr[0] = *(const float4*)&wloc[tap*DH + c8*8];
        *(float4*)&wr[4] = *(const float4*)&wloc[tap*DH + c8*8 + 4];
#pragma unroll
        for (int j = 0; j < 8; ++j)
            acc[j] += b2f(iv[tap][j]) * wr[j];
    }
    u16x8 ov;
#pragma unroll
    for (int j = 0; j < 8; ++j) ov[j] = f2b(acc[j]);
    *(u16x8*)(out + plane + (size_t)p*DH + c8*8) = ov;
}

// ---------------------------------------------------------------------------
// K3: per-(window, head) channel attention; head-separated I/O. (R4/R12)
// ---------------------------------------------------------------------------
__global__ __launch_bounds__(256) void attn_kernel(
    const u16* __restrict__ q, const u16* __restrict__ k, const u16* __restrict__ v,
    const float* __restrict__ rescale, u16* __restrict__ out)
{
    __shared__ float qt[DH][260];
    __shared__ float kt[DH][260];
    float* pbuf = &kt[0][0];            // reused: partials[4*576] + sim/attn[576]
    const int t    = threadIdx.x;
    const int widx = blockIdx.x;        // b*256 + wy*16 + wx
    const int h    = blockIdx.y;
    const int b  = widx >> 8;
    const int wy = (widx >> 4) & 15, wx = widx & 15;
    const int n  = t;
    const int gy = wy*WIN + (n >> 4), gx = wx*WIN + (n & 15);
    const size_t pbase = (size_t)h*PS + (size_t)((b*NHH + gy)*NWW + gx) * DH;

    // phase A: q,k transposed into LDS (fp32)
#pragma unroll
    for (int j8 = 0; j8 < 3; ++j8) {
        const u16x8 qv = *(const u16x8*)(q + pbase + j8*8);
        const u16x8 kv = *(const u16x8*)(k + pbase + j8*8);
#pragma unroll
        for (int j = 0; j < 8; ++j) { qt[j8*8+j][n] = b2f(qv[j]); kt[j8*8+j][n] = b2f(kv[j]); }
    }
    __syncthreads();

    // phase B: sim partials; wave covers 64 of n, thread = 3x3 (i,j) block
    const int wvi  = t >> 6;
    const int lane = t & 63;
    const int i0 = (lane >> 3) * 3, j0 = (lane & 7) * 3;
    float s[3][3];
#pragma unroll
    for (int a2 = 0; a2 < 3; ++a2)
#pragma unroll
        for (int c = 0; c < 3; ++c) s[a2][c] = 0.f;
    for (int nn = wvi*64; nn < wvi*64 + 64; nn += 4) {
        float4 qv[3], kv[3];
#pragma unroll
        for (int a2 = 0; a2 < 3; ++a2) {
            qv[a2] = *(const float4*)&qt[i0+a2][nn];
            kv[a2] = *(const float4*)&kt[j0+a2][nn];
        }
#pragma unroll
        for (int a2 = 0; a2 < 3; ++a2)
#pragma unroll
            for (int c = 0; c < 3; ++c)
                s[a2][c] += qv[a2].x*kv[c].x + qv[a2].y*kv[c].y + qv[a2].z*kv[c].z + qv[a2].w*kv[c].w;
    }
    __syncthreads();

    // phase C: partials -> kt-flat; v -> qt
#pragma unroll
    for (int a2 = 0; a2 < 3; ++a2)
#pragma unroll
        for (int c = 0; c < 3; ++c)
            pbuf[wvi*576 + (i0+a2)*24 + (j0+c)] = s[a2][c];
#pragma unroll
    for (int j8 = 0; j8 < 3; ++j8) {
        const u16x8 vv = *(const u16x8*)(v + pbase + j8*8);
#pragma unroll
        for (int j = 0; j < 8; ++j) qt[j8*8+j][n] = b2f(vv[j]);
    }
    __syncthreads();

    // phase D: reduce 4 wave-partials + rescale
    const float rsc = rescale[h];
    for (int e = t; e < 576; e += 256) {
        const float sum = pbuf[e] + pbuf[576+e] + pbuf[1152+e] + pbuf[1728+e];
        pbuf[2304 + e] = sum * rsc;
    }
    __syncthreads();

    // phase E: softmax over j per row i
    if (t < 24) {
        float* srow = pbuf + 2304 + t*24;
        float m = srow[0];
#pragma unroll
        for (int j = 1; j < 24; ++j) m = fmaxf(m, srow[j]);
        float ssum = 0.f;
#pragma unroll
        for (int j = 0; j < 24; ++j) { const float e_ = expf(srow[j] - m); srow[j] = e_; ssum += e_; }
        const float inv = 1.f / ssum;
#pragma unroll
        for (int j = 0; j < 24; ++j) srow[j] *= inv;
    }
    __syncthreads();

    // phase F: PV — thread (iw,nc): 6 i-rows x one 4-wide n-chunk
    const int nc = t & 63;
    const int ib = (t >> 6) * 6;
    float4 acc[6];
#pragma unroll
    for (int ii = 0; ii < 6; ++ii) acc[ii] = make_float4(0.f,0.f,0.f,0.f);
#pragma unroll
    for (int j = 0; j < 24; ++j) {
        const float4 vj = *(const float4*)&qt[j][nc*4];
        const float aw0 = pbuf[2304 + (ib+0)*24 + j];
        const float aw1 = pbuf[2304 + (ib+1)*24 + j];
        const float aw2 = pbuf[2304 + (ib+2)*24 + j];
        const float aw3 = pbuf[2304 + (ib+3)*24 + j];
        const float aw4 = pbuf[2304 + (ib+4)*24 + j];
        const float aw5 = pbuf[2304 + (ib+5)*24 + j];
        acc[0].x += aw0*vj.x; acc[0].y += aw0*vj.y; acc[0].z += aw0*vj.z; acc[0].w += aw0*vj.w;
        acc[1].x += aw1*vj.x; acc[1].y += aw1*vj.y; acc[1].z += aw1*vj.z; acc[1].w += aw1*vj.w;
        acc[2].x += aw2*vj.x; acc[2].y += aw2*vj.y; acc[2].z += aw2*vj.z; acc[2].w += aw2*vj.w;
        acc[3].x += aw3*vj.x; acc[3].y += aw3*vj.y; acc[3].z += aw3*vj.z; acc[3].w += aw3*vj.w;
        acc[4].x += aw4*vj.x; acc[4].y += aw4*vj.y; acc[4].z += aw4*vj.z; acc[4].w += aw4*vj.w;
        acc[5].x += aw5*vj.x; acc[5].y += aw5*vj.y; acc[5].z += aw5*vj.z; acc[5].w += aw5*vj.w;
    }
    __syncthreads();
    // phase G: stage output fp32 into qt
#pragma unroll
    for (int ii = 0; ii < 6; ++ii)
        *(float4*)&qt[ib+ii][nc*4] = acc[ii];
    __syncthreads();
    // phase H: coalesced bf16 store (3KB contiguous per wave)
#pragma unroll
    for (int j8 = 0; j8 < 3; ++j8) {
        u16x8 o;
#pragma unroll
        for (int j = 0; j < 8; ++j) o[j] = f2b(qt[j8*8+j][n]);
        *(u16x8*)(out + pbase + j8*8) = o;
    }
}

// ---------------------------------------------------------------------------
// K4: out-projection MFMA GEMM with LDS-staged A (coalesced) + staged fp32 out.
// ---------------------------------------------------------------------------
__global__ __launch_bounds__(256) void outproj_gemm(
    const u16* __restrict__ a, const u16* __restrict__ bpack, float* __restrict__ yf)
{
    __shared__ __align__(16) u16 At[64*192];    // 24,576 B (swizzled)
    __shared__ __align__(16) float Sf[32*196];  // 25,088 B
    const int t = threadIdx.x, l = t & 63, w = t >> 6;
    const int lr = l & 15, lg = l >> 4;
    const size_t p0 = (size_t)blockIdx.x * 64;

    // stage A-tile: coalesced within head planes (contiguous 4.6KB per plane)
#pragma unroll
    for (int i = 0; i < 6; ++i) {
        const int idx = t + i*256;          // 0..1535 = h*192 + r*3 + c8
        const int h = idx / 192;
        const int rem = idx - h*192;
        const int r = rem / 3, c8 = rem - r*3;
        const u16x8 vv = *(const u16x8*)(a + (size_t)h*PS + (p0 + r)*DH + c8*8);
        *(u16x8*)&At[r*192 + (((h*3 + c8) ^ (r & 7))*8)] = vv;
    }
    __syncthreads();

    f32x4 acc[4][3];
#pragma unroll
    for (int mt = 0; mt < 4; ++mt)
#pragma unroll
        for (int nt = 0; nt < 3; ++nt) acc[mt][nt] = (f32x4){0.f,0.f,0.f,0.f};
    const u16* bp = bpack + (size_t)3*36864 + (size_t)w*3*3072 + l*8;
#pragma unroll
    for (int ks = 0; ks < 6; ++ks) {
        bf16x8 af[4], bfr[3];
#pragma unroll
        for (int nt = 0; nt < 3; ++nt)
            bfr[nt] = *(const bf16x8*)(bp + (size_t)nt*3072 + ks*512);
#pragma unroll
        for (int mt = 0; mt < 4; ++mt)
            af[mt] = *(const bf16x8*)&At[(mt*16 + lr)*192 + ((ks*4 + lg) ^ (lr & 7))*8];
#pragma unroll
        for (int mt = 0; mt < 4; ++mt)
#pragma unroll
            for (int nt = 0; nt < 3; ++nt)
                acc[mt][nt] = __builtin_amdgcn_mfma_f32_16x16x32_bf16(
                    af[mt], bfr[nt], acc[mt][nt], 0, 0, 0);
    }
    // D layout: position = mt*16 + lg*4 + reg, channel = (w*3+nt)*16 + lr
#pragma unroll
    for (int h2 = 0; h2 < 2; ++h2) {
        if (h2) __syncthreads();            // prev drain readers done
#pragma unroll
        for (int mi = 0; mi < 2; ++mi) {
            const int mt = h2*2 + mi;
#pragma unroll
            for (int nt = 0; nt < 3; ++nt)
#pragma unroll
                for (int reg = 0; reg < 4; ++reg)
                    Sf[(mi*16 + lg*4 + reg)*196 + (w*3 + nt)*16 + lr] = acc[mt][nt][reg];
        }
        __syncthreads();
        // drain: 32 rows x 192 ch fp32, fully contiguous 4KB runs
#pragma unroll
        for (int i = 0; i < 6; ++i) {
            const int f = t + i*256;        // 32 rows x 48 float4
            const int row = f / 48, c4 = f - row*48;
            *(float4*)(yf + (p0 + h2*32 + row)*CH + c4*4) = *(const float4*)&Sf[row*196 + c4*4];
        }
    }
}

// ---------------------------------------------------------------------------
extern "C" void kernel_launch(void* const* d_in, const int* in_sizes, int n_in,
                              void* d_out, int out_size, void* d_ws, size_t ws_size,
                              hipStream_t stream)
{
    (void)in_sizes; (void)n_in; (void)out_size; (void)ws_size;
    const float* x     = (const float*)d_in[0];
    const float* ln_g  = (const float*)d_in[1];
    const float* ln_b  = (const float*)d_in[2];
    const float* wq1   = (const float*)d_in[3];
    const float* wq2   = (const float*)d_in[4];
    const float* wk1   = (const float*)d_in[5];
    const float* wk2   = (const float*)d_in[6];
    const float* wv1   = (const float*)d_in[7];
    const float* wv2   = (const float*)d_in[8];
    const float* rsc   = (const float*)d_in[9];
    const float* w_out = (const float*)d_in[10];
    float* out = (float*)d_out;

    const size_t NT = (size_t)NPOS * CH;    // 50,331,648 elems
    u16* u1 = (u16*)d_ws;                   // q,k,v pre-dwconv (head-sep)
    u16* u2 = u1 + NT;
    u16* u3 = u2 + NT;
    u16* u4 = u3 + NT;                      // q,k,v post-dwconv (disjoint)
    u16* u5 = u4 + NT;
    u16* u6 = u5 + NT;
    u16* pack = u6 + NT;                    // 147,456 u16
    u16* zpage = pack + 147456;             // 512 B zero page (16B-aligned)

    hipMemsetAsync(zpage, 0, 512, stream);
    prep_weights<<<72, 256, 0, stream>>>(wq1, wk1, wv1, w_out, pack);
    // fused LN + QKV GEMM -> head-separated q,k,v
    ln_qkv_gemm<<<NPOS/32, 256, 0, stream>>>(x, ln_g, ln_b, pack, u1, u2, u3);
    // depthwise 3x3, one dispatch (z = tensor): u1->u4, u2->u5, u3->u6
    dwconv_all<<<dim3(NPOS*3/256, HEADS, 3), 256, 0, stream>>>(
        u1, u2, u3, wq2, wk2, wv2, u4, u5, u6, zpage);
    // windowed channel attention: q=u4, k=u5, v=u6 -> u1 (head-sep)
    attn_kernel<<<dim3(NB*256, HEADS), 256, 0, stream>>>(u4, u5, u6, rsc, u1);
    // output projection (A staged in LDS, fp32 NHWC out)
    outproj_gemm<<<NPOS/64, 256, 0, stream>>>(u1, pack, out);
}

// Round 17
// 559.045 us; speedup vs baseline: 1.6690x; 1.0101x over previous
//
#include <hip/hip_runtime.h>
#include <hip/hip_bf16.h>

#define CH    192
#define NB    4
#define NHH   256
#define NWW   256
#define NPOS  (NB*NHH*NWW)   // 262144
#define HEADS 8
#define DH    24
#define WIN   16
#define PS    ((size_t)NPOS*DH)   // head-plane stride (elems)

typedef unsigned short u16;
typedef unsigned int   u32;
typedef __bf16 bf16x8 __attribute__((ext_vector_type(8)));
typedef float  f32x4  __attribute__((ext_vector_type(4)));
typedef float  f32x2  __attribute__((ext_vector_type(2)));
typedef u16    u16x8  __attribute__((ext_vector_type(8)));
typedef u16    u16x4  __attribute__((ext_vector_type(4)));

__device__ __forceinline__ float b2f(u16 h) {
    union { unsigned int u; float f; } x; x.u = ((unsigned int)h) << 16; return x.f;
}
__device__ __forceinline__ u16 f2b(float f) {   // RNE
    union { float f; unsigned int u; } x; x.f = f;
    return (u16)((x.u + 0x7fffu + ((x.u >> 16) & 1u)) >> 16);
}
__device__ __forceinline__ float asf(u32 u) {
    union { u32 u; float f; } x; x.u = u; return x.f;
}

// ---------------------------------------------------------------------------
// P0: pack 4 weight matrices (fp32 [o][i]) into MFMA fragment order, bf16.
// ---------------------------------------------------------------------------
__global__ __launch_bounds__(256) void prep_weights(
    const float* __restrict__ w0, const float* __restrict__ w1,
    const float* __restrict__ w2, const float* __restrict__ w3,
    u16* __restrict__ pack)
{
    const int t = blockIdx.x * 256 + threadIdx.x;   // 18432 total
    const int lane = t & 63, g = t >> 6;            // g: 0..287
    const int mat = g / 72;
    const float* w = (mat == 0) ? w0 : (mat == 1) ? w1 : (mat == 2) ? w2 : w3;
    const int nt = (g / 6) % 12, ks = g % 6;
    const float* src = w + (nt*16 + (lane & 15)) * CH + ks*32 + (lane >> 4) * 8;
    const float4 a = *(const float4*)(src);
    const float4 b = *(const float4*)(src + 4);
    u16x8 o;
    o[0]=f2b(a.x); o[1]=f2b(a.y); o[2]=f2b(a.z); o[3]=f2b(a.w);
    o[4]=f2b(b.x); o[5]=f2b(b.y); o[6]=f2b(b.z); o[7]=f2b(b.w);
    *(u16x8*)(pack + (size_t)g*512 + lane*8) = o;
}

// ---------------------------------------------------------------------------
// K1: fused LayerNorm + QKV MFMA GEMM (operand-swapped: D = W * X^T).
// M=32 tile, At swizzled, St32 full drain, 25.1 KB LDS, lb(256,6). ~195 us.
// Ledger: conflicts null (R6), occupancy-8blk slower (R14). Done.
// ---------------------------------------------------------------------------
__global__ __launch_bounds__(256, 6) void ln_qkv_gemm(
    const float* __restrict__ x, const float* __restrict__ lng, const float* __restrict__ lnb,
    const u16* __restrict__ bpack,
    u16* __restrict__ y0, u16* __restrict__ y1, u16* __restrict__ y2)
{
    __shared__ __align__(16) u16 At[32*192];    // 12,288 B (swizzled)
    __shared__ __align__(16) u16 St32[32*200];  // 12,800 B
    const int t = threadIdx.x, l = t & 63, w = t >> 6;
    const int lr = l & 15, lg = l >> 4;
    const size_t p0 = (size_t)blockIdx.x * 32;

    // ---- LN phase: 8 lanes per row (24 ch each), shfl-reduce, bf16 -> At ----
    {
        const int row = t >> 3, part = t & 7;
        const float* xp = x + (p0 + row) * CH + part * 24;
        float vals[24];
#pragma unroll
        for (int j = 0; j < 6; ++j) {
            float4 v4 = *(const float4*)(xp + j * 4);
            vals[j*4+0]=v4.x; vals[j*4+1]=v4.y; vals[j*4+2]=v4.z; vals[j*4+3]=v4.w;
        }
        float s = 0.f, s2 = 0.f;
#pragma unroll
        for (int j = 0; j < 24; ++j) { s += vals[j]; s2 += vals[j]*vals[j]; }
        s += __shfl_xor(s, 1);  s2 += __shfl_xor(s2, 1);
        s += __shfl_xor(s, 2);  s2 += __shfl_xor(s2, 2);
        s += __shfl_xor(s, 4);  s2 += __shfl_xor(s2, 4);
        const float mu = s * (1.f/192.f);
        const float rs = rsqrtf(s2 * (1.f/192.f) - mu*mu + 1e-5f);
#pragma unroll
        for (int jb = 0; jb < 3; ++jb) {
            u16x8 o;
#pragma unroll
            for (int j = 0; j < 8; ++j) {
                const int c = part*24 + jb*8 + j;
                o[j] = f2b((vals[jb*8+j] - mu) * rs * lng[c] + lnb[c]);
            }
            const int cb = part*3 + jb;               // 0..23
            *(u16x8*)&At[row*192 + (cb ^ (row & 7))*8] = o;
        }
    }
    __syncthreads();

    // ---- GEMM over 3 weight matrices (operand-swapped) ----
    for (int mat = 0; mat < 3; ++mat) {
        u16* yb = (mat == 0) ? y0 : (mat == 1) ? y1 : y2;
        f32x4 acc[2][3];
#pragma unroll
        for (int mt = 0; mt < 2; ++mt)
#pragma unroll
            for (int nt = 0; nt < 3; ++nt) acc[mt][nt] = (f32x4){0.f,0.f,0.f,0.f};
        const u16* bp = bpack + (size_t)mat*36864 + (size_t)w*3*3072 + l*8;
#pragma unroll
        for (int ks = 0; ks < 6; ++ks) {
            bf16x8 wf[3], xf[2];
#pragma unroll
            for (int nt = 0; nt < 3; ++nt)
                wf[nt] = *(const bf16x8*)(bp + (size_t)nt*3072 + ks*512);
#pragma unroll
            for (int mt = 0; mt < 2; ++mt)
                xf[mt] = *(const bf16x8*)&At[(mt*16 + lr)*192 + ((ks*4 + lg) ^ (lr & 7))*8];
#pragma unroll
            for (int mt = 0; mt < 2; ++mt)
#pragma unroll
                for (int nt = 0; nt < 3; ++nt)   // D = W-frag * X-frag
                    acc[mt][nt] = __builtin_amdgcn_mfma_f32_16x16x32_bf16(
                        wf[nt], xf[mt], acc[mt][nt], 0, 0, 0);
        }
        // D layout: position = mt*16 + lr, channel = (w*3+nt)*16 + lg*4 + reg
        __syncthreads();                 // St32 free (prev mat's drain done)
#pragma unroll
        for (int mt = 0; mt < 2; ++mt)
#pragma unroll
            for (int nt = 0; nt < 3; ++nt) {
                u16x4 pk;
                pk[0] = f2b(acc[mt][nt][0]); pk[1] = f2b(acc[mt][nt][1]);
                pk[2] = f2b(acc[mt][nt][2]); pk[3] = f2b(acc[mt][nt][3]);
                *(u16x4*)&St32[(mt*16 + lr)*200 + (w*3 + nt)*16 + lg*4] = pk;
            }
        __syncthreads();
        // drain: 256 threads = 8 heads x 32 rows, 48B contiguous each
        {
            const int hh = t >> 5, r = t & 31;
            u16* dst = yb + (size_t)hh*PS + (p0 + r)*DH;
#pragma unroll
            for (int j8 = 0; j8 < 3; ++j8)
                *(u16x8*)(dst + j8*8) = *(const u16x8*)&St32[r*200 + hh*24 + j8*8];
        }
    }
}

// ---------------------------------------------------------------------------
// K2: 3x3 depthwise conv per head-plane [h][b][y][x][24], bf16, fp32 accum.
// R12 structure (LDS weights, batched iv[9], zpage, XCD band swizzle) with
// VALU-thinned consumption: bf16 PAIRS unpacked via {v<<16, v&0xffff0000}
// (2 ops/pair, no per-element shifts) into f32x2 and accumulated with
// f32x2 math -> v_pk_fma_f32 (2 FMA/inst on CDNA4). Per pair-tap: 3 VALU
// vs 4+ before (~30% cut on the dominant loop). Loads/stores unchanged.
// ---------------------------------------------------------------------------
__global__ __launch_bounds__(256, 4) void dwconv_all(
    const u16* __restrict__ in0, const u16* __restrict__ in1, const u16* __restrict__ in2,
    const float* __restrict__ w0, const float* __restrict__ w1, const float* __restrict__ w2,
    u16* __restrict__ out0, u16* __restrict__ out1, u16* __restrict__ out2,
    const u16* __restrict__ zpage)
{
    __shared__ __align__(16) float wloc[9*DH];   // [tap][c], 864 B
    const int z = blockIdx.z;
    const u16* in  = (z == 0) ? in0  : (z == 1) ? in1  : in2;
    const float* wdw = (z == 0) ? w0 : (z == 1) ? w1 : w2;
    u16* out       = (z == 0) ? out0 : (z == 1) ? out1 : out2;
    const int t = threadIdx.x;
    const int h = blockIdx.y;
    if (t < 216) {                        // wdw layout [c][tap] -> wloc [tap][c]
        const int c = t / 9, tap = t - c*9;
        wloc[tap*DH + c] = wdw[h*216 + t];
    }
    __syncthreads();
    const int NSLICE = NPOS*3/256;           // 3072 blocks per (h,z) slice
    const int CPX = NSLICE/8;                // 384 contiguous blocks per XCD
    const int bx = blockIdx.x;
    const int swz = (bx & 7)*CPX + (bx >> 3);
    const int gid2 = swz * 256 + t;          // in [0, NPOS*3)
    const int p  = gid2 / 3, c8 = gid2 - p*3;
    const int x = p & 255, y = (p >> 8) & 255, b = p >> 16;
    const size_t plane = (size_t)h * PS;

    // issue all 9 tap loads (borders -> zero page), then one wait
    u16x8 iv[9];
#pragma unroll
    for (int ky = 0; ky < 3; ++ky) {
        const int yy = y + ky - 1;
        const bool oky = (yy >= 0) && (yy < NHH);
        const u16* rowp = in + plane + (size_t)((b*NHH + yy)*NWW + x)*DH + c8*8;
#pragma unroll
        for (int kx = 0; kx < 3; ++kx) {
            const int xx = x + kx - 1;
            const bool ok = oky && (xx >= 0) && (xx < NWW);
            const u16* src = ok ? (rowp + (kx - 1)*DH) : zpage;
            iv[ky*3 + kx] = *(const u16x8*)src;
        }
    }
    // consumption: pair-unpack + packed-f32 FMA
    f32x2 acc2[4];
#pragma unroll
    for (int pq = 0; pq < 4; ++pq) acc2[pq] = (f32x2){0.f, 0.f};
#pragma unroll
    for (int tap = 0; tap < 9; ++tap) {
        float wr[8];
        *(float4*)&wr[0] = *(const float4*)&wloc[tap*DH + c8*8];
        *(float4*)&wr[4] = *(const float4*)&wloc[tap*DH + c8*8 + 4];
        const u32* pv = (const u32*)&iv[tap];
#pragma unroll
        for (int pq = 0; pq < 4; ++pq) {
            const u32 v = pv[pq];
            f32x2 xv;
            xv[0] = asf(v << 16);            // lo bf16 -> f32 (exact)
            xv[1] = asf(v & 0xffff0000u);    // hi bf16 -> f32 (exact, no shift)
            f32x2 wv;
            wv[0] = wr[pq*2]; wv[1] = wr[pq*2 + 1];
            acc2[pq] += xv * wv;             // v_pk_fma_f32
        }
    }
    u16x8 ov;
#pragma unroll
    for (int pq = 0; pq < 4; ++pq) {
        ov[pq*2]     = f2b(acc2[pq][0]);
        ov[pq*2 + 1] = f2b(acc2[pq][1]);
    }
    *(u16x8*)(out + plane + (size_t)p*DH + c8*8) = ov;
}

// ---------------------------------------------------------------------------
// K3: per-(window, head) channel attention; head-separated I/O. (R4/R12)
// ---------------------------------------------------------------------------
__global__ __launch_bounds__(256) void attn_kernel(
    const u16* __restrict__ q, const u16* __restrict__ k, const u16* __restrict__ v,
    const float* __restrict__ rescale, u16* __restrict__ out)
{
    __shared__ float qt[DH][260];
    __shared__ float kt[DH][260];
    float* pbuf = &kt[0][0];            // reused: partials[4*576] + sim/attn[576]
    const int t    = threadIdx.x;
    const int widx = blockIdx.x;        // b*256 + wy*16 + wx
    const int h    = blockIdx.y;
    const int b  = widx >> 8;
    const int wy = (widx >> 4) & 15, wx = widx & 15;
    const int n  = t;
    const int gy = wy*WIN + (n >> 4), gx = wx*WIN + (n & 15);
    const size_t pbase = (size_t)h*PS + (size_t)((b*NHH + gy)*NWW + gx) * DH;

    // phase A: q,k transposed into LDS (fp32)
#pragma unroll
    for (int j8 = 0; j8 < 3; ++j8) {
        const u16x8 qv = *(const u16x8*)(q + pbase + j8*8);
        const u16x8 kv = *(const u16x8*)(k + pbase + j8*8);
#pragma unroll
        for (int j = 0; j < 8; ++j) { qt[j8*8+j][n] = b2f(qv[j]); kt[j8*8+j][n] = b2f(kv[j]); }
    }
    __syncthreads();

    // phase B: sim partials; wave covers 64 of n, thread = 3x3 (i,j) block
    const int wvi  = t >> 6;
    const int lane = t & 63;
    const int i0 = (lane >> 3) * 3, j0 = (lane & 7) * 3;
    float s[3][3];
#pragma unroll
    for (int a2 = 0; a2 < 3; ++a2)
#pragma unroll
        for (int c = 0; c < 3; ++c) s[a2][c] = 0.f;
    for (int nn = wvi*64; nn < wvi*64 + 64; nn += 4) {
        float4 qv[3], kv[3];
#pragma unroll
        for (int a2 = 0; a2 < 3; ++a2) {
            qv[a2] = *(const float4*)&qt[i0+a2][nn];
            kv[a2] = *(const float4*)&kt[j0+a2][nn];
        }
#pragma unroll
        for (int a2 = 0; a2 < 3; ++a2)
#pragma unroll
            for (int c = 0; c < 3; ++c)
                s[a2][c] += qv[a2].x*kv[c].x + qv[a2].y*kv[c].y + qv[a2].z*kv[c].z + qv[a2].w*kv[c].w;
    }
    __syncthreads();

    // phase C: partials -> kt-flat; v -> qt
#pragma unroll
    for (int a2 = 0; a2 < 3; ++a2)
#pragma unroll
        for (int c = 0; c < 3; ++c)
            pbuf[wvi*576 + (i0+a2)*24 + (j0+c)] = s[a2][c];
#pragma unroll
    for (int j8 = 0; j8 < 3; ++j8) {
        const u16x8 vv = *(const u16x8*)(v + pbase + j8*8);
#pragma unroll
        for (int j = 0; j < 8; ++j) qt[j8*8+j][n] = b2f(vv[j]);
    }
    __syncthreads();

    // phase D: reduce 4 wave-partials + rescale
    const float rsc = rescale[h];
    for (int e = t; e < 576; e += 256) {
        const float sum = pbuf[e] + pbuf[576+e] + pbuf[1152+e] + pbuf[1728+e];
        pbuf[2304 + e] = sum * rsc;
    }
    __syncthreads();

    // phase E: softmax over j per row i
    if (t < 24) {
        float* srow = pbuf + 2304 + t*24;
        float m = srow[0];
#pragma unroll
        for (int j = 1; j < 24; ++j) m = fmaxf(m, srow[j]);
        float ssum = 0.f;
#pragma unroll
        for (int j = 0; j < 24; ++j) { const float e_ = expf(srow[j] - m); srow[j] = e_; ssum += e_; }
        const float inv = 1.f / ssum;
#pragma unroll
        for (int j = 0; j < 24; ++j) srow[j] *= inv;
    }
    __syncthreads();

    // phase F: PV — thread (iw,nc): 6 i-rows x one 4-wide n-chunk
    const int nc = t & 63;
    const int ib = (t >> 6) * 6;
    float4 acc[6];
#pragma unroll
    for (int ii = 0; ii < 6; ++ii) acc[ii] = make_float4(0.f,0.f,0.f,0.f);
#pragma unroll
    for (int j = 0; j < 24; ++j) {
        const float4 vj = *(const float4*)&qt[j][nc*4];
        const float aw0 = pbuf[2304 + (ib+0)*24 + j];
        const float aw1 = pbuf[2304 + (ib+1)*24 + j];
        const float aw2 = pbuf[2304 + (ib+2)*24 + j];
        const float aw3 = pbuf[2304 + (ib+3)*24 + j];
        const float aw4 = pbuf[2304 + (ib+4)*24 + j];
        const float aw5 = pbuf[2304 + (ib+5)*24 + j];
        acc[0].x += aw0*vj.x; acc[0].y += aw0*vj.y; acc[0].z += aw0*vj.z; acc[0].w += aw0*vj.w;
        acc[1].x += aw1*vj.x; acc[1].y += aw1*vj.y; acc[1].z += aw1*vj.z; acc[1].w += aw1*vj.w;
        acc[2].x += aw2*vj.x; acc[2].y += aw2*vj.y; acc[2].z += aw2*vj.z; acc[2].w += aw2*vj.w;
        acc[3].x += aw3*vj.x; acc[3].y += aw3*vj.y; acc[3].z += aw3*vj.z; acc[3].w += aw3*vj.w;
        acc[4].x += aw4*vj.x; acc[4].y += aw4*vj.y; acc[4].z += aw4*vj.z; acc[4].w += aw4*vj.w;
        acc[5].x += aw5*vj.x; acc[5].y += aw5*vj.y; acc[5].z += aw5*vj.z; acc[5].w += aw5*vj.w;
    }
    __syncthreads();
    // phase G: stage output fp32 into qt
#pragma unroll
    for (int ii = 0; ii < 6; ++ii)
        *(float4*)&qt[ib+ii][nc*4] = acc[ii];
    __syncthreads();
    // phase H: coalesced bf16 store (3KB contiguous per wave)
#pragma unroll
    for (int j8 = 0; j8 < 3; ++j8) {
        u16x8 o;
#pragma unroll
        for (int j = 0; j < 8; ++j) o[j] = f2b(qt[j8*8+j][n]);
        *(u16x8*)(out + pbase + j8*8) = o;
    }
}

// ---------------------------------------------------------------------------
// K4: out-projection MFMA GEMM with LDS-staged A (coalesced) + staged fp32 out.
// ---------------------------------------------------------------------------
__global__ __launch_bounds__(256) void outproj_gemm(
    const u16* __restrict__ a, const u16* __restrict__ bpack, float* __restrict__ yf)
{
    __shared__ __align__(16) u16 At[64*192];    // 24,576 B (swizzled)
    __shared__ __align__(16) float Sf[32*196];  // 25,088 B
    const int t = threadIdx.x, l = t & 63, w = t >> 6;
    const int lr = l & 15, lg = l >> 4;
    const size_t p0 = (size_t)blockIdx.x * 64;

    // stage A-tile: coalesced within head planes (contiguous 4.6KB per plane)
#pragma unroll
    for (int i = 0; i < 6; ++i) {
        const int idx = t + i*256;          // 0..1535 = h*192 + r*3 + c8
        const int h = idx / 192;
        const int rem = idx - h*192;
        const int r = rem / 3, c8 = rem - r*3;
        const u16x8 vv = *(const u16x8*)(a + (size_t)h*PS + (p0 + r)*DH + c8*8);
        *(u16x8*)&At[r*192 + (((h*3 + c8) ^ (r & 7))*8)] = vv;
    }
    __syncthreads();

    f32x4 acc[4][3];
#pragma unroll
    for (int mt = 0; mt < 4; ++mt)
#pragma unroll
        for (int nt = 0; nt < 3; ++nt) acc[mt][nt] = (f32x4){0.f,0.f,0.f,0.f};
    const u16* bp = bpack + (size_t)3*36864 + (size_t)w*3*3072 + l*8;
#pragma unroll
    for (int ks = 0; ks < 6; ++ks) {
        bf16x8 af[4], bfr[3];
#pragma unroll
        for (int nt = 0; nt < 3; ++nt)
            bfr[nt] = *(const bf16x8*)(bp + (size_t)nt*3072 + ks*512);
#pragma unroll
        for (int mt = 0; mt < 4; ++mt)
            af[mt] = *(const bf16x8*)&At[(mt*16 + lr)*192 + ((ks*4 + lg) ^ (lr & 7))*8];
#pragma unroll
        for (int mt = 0; mt < 4; ++mt)
#pragma unroll
            for (int nt = 0; nt < 3; ++nt)
                acc[mt][nt] = __builtin_amdgcn_mfma_f32_16x16x32_bf16(
                    af[mt], bfr[nt], acc[mt][nt], 0, 0, 0);
    }
    // D layout: position = mt*16 + lg*4 + reg, channel = (w*3+nt)*16 + lr
#pragma unroll
    for (int h2 = 0; h2 < 2; ++h2) {
        if (h2) __syncthreads();            // prev drain readers done
#pragma unroll
        for (int mi = 0; mi < 2; ++mi) {
            const int mt = h2*2 + mi;
#pragma unroll
            for (int nt = 0; nt < 3; ++nt)
#pragma unroll
                for (int reg = 0; reg < 4; ++reg)
                    Sf[(mi*16 + lg*4 + reg)*196 + (w*3 + nt)*16 + lr] = acc[mt][nt][reg];
        }
        __syncthreads();
        // drain: 32 rows x 192 ch fp32, fully contiguous 4KB runs
#pragma unroll
        for (int i = 0; i < 6; ++i) {
            const int f = t + i*256;        // 32 rows x 48 float4
            const int row = f / 48, c4 = f - row*48;
            *(float4*)(yf + (p0 + h2*32 + row)*CH + c4*4) = *(const float4*)&Sf[row*196 + c4*4];
        }
    }
}

// ---------------------------------------------------------------------------
extern "C" void kernel_launch(void* const* d_in, const int* in_sizes, int n_in,
                              void* d_out, int out_size, void* d_ws, size_t ws_size,
                              hipStream_t stream)
{
    (void)in_sizes; (void)n_in; (void)out_size; (void)ws_size;
    const float* x     = (const float*)d_in[0];
    const float* ln_g  = (const float*)d_in[1];
    const float* ln_b  = (const float*)d_in[2];
    const float* wq1   = (const float*)d_in[3];
    const float* wq2   = (const float*)d_in[4];
    const float* wk1   = (const float*)d_in[5];
    const float* wk2   = (const float*)d_in[6];
    const float* wv1   = (const float*)d_in[7];
    const float* wv2   = (const float*)d_in[8];
    const float* rsc   = (const float*)d_in[9];
    const float* w_out = (const float*)d_in[10];
    float* out = (float*)d_out;

    const size_t NT = (size_t)NPOS * CH;    // 50,331,648 elems
    u16* u1 = (u16*)d_ws;                   // q,k,v pre-dwconv (head-sep)
    u16* u2 = u1 + NT;
    u16* u3 = u2 + NT;
    u16* u4 = u3 + NT;                      // q,k,v post-dwconv (disjoint)
    u16* u5 = u4 + NT;
    u16* u6 = u5 + NT;
    u16* pack = u6 + NT;                    // 147,456 u16
    u16* zpage = pack + 147456;             // 512 B zero page (16B-aligned)

    hipMemsetAsync(zpage, 0, 512, stream);
    prep_weights<<<72, 256, 0, stream>>>(wq1, wk1, wv1, w_out, pack);
    // fused LN + QKV GEMM -> head-separated q,k,v
    ln_qkv_gemm<<<NPOS/32, 256, 0, stream>>>(x, ln_g, ln_b, pack, u1, u2, u3);
    // depthwise 3x3, one dispatch (z = tensor): u1->u4, u2->u5, u3->u6
    dwconv_all<<<dim3(NPOS*3/256, HEADS, 3), 256, 0, stream>>>(
        u1, u2, u3, wq2, wk2, wv2, u4, u5, u6, zpage);
    // windowed channel attention: q=u4, k=u5, v=u6 -> u1 (head-sep)
    attn_kernel<<<dim3(NB*256, HEADS), 256, 0, stream>>>(u4, u5, u6, rsc, u1);
    // output projection (A staged in LDS, fp32 NHWC out)
    outproj_gemm<<<NPOS/64, 256, 0, stream>>>(u1, pack, out);
}